// Round 1
// baseline (5056.340 us; speedup 1.0000x reference)
//
#include <hip/hip_runtime.h>
#include <cstddef>

// Problem constants (B,S,D,H,F) = (4,1024,1024,16,4096)
#define D_MODEL 1024
#define SEQ     1024
#define BATCH   4
#define NHEAD   16
#define DH      64
#define FFDIM   4096
#define NTOK    (BATCH*SEQ)   // 4096 tokens

__device__ __forceinline__ float silu_f(float x){ return x / (1.f + __expf(-x)); }

// ---------------- ada = silu(t_emb) @ ada_w + ada_b  -> [B, 6D] ----------------
__global__ __launch_bounds__(256) void ada_kernel(
    const float* __restrict__ t_emb, const float* __restrict__ W,
    const float* __restrict__ bias, float* __restrict__ out){
  __shared__ float st[D_MODEL];
  int b = blockIdx.y;
  for (int i = threadIdx.x; i < D_MODEL; i += 256){
    float v = t_emb[b*D_MODEL + i];
    st[i] = silu_f(v);
  }
  __syncthreads();
  int n = blockIdx.x*256 + threadIdx.x;
  float acc = bias[n];
  for (int k = 0; k < D_MODEL; ++k)
    acc += st[k] * W[(size_t)k*(6*D_MODEL) + n];
  out[(size_t)b*(6*D_MODEL) + n] = acc;
}

// ---------------- nx = ln(x)*g+b, then *(1+sc)+sh (AdaLN modulation) ----------------
__global__ __launch_bounds__(256) void ln_mod_kernel(
    const float* __restrict__ x, const float* __restrict__ g, const float* __restrict__ bta,
    const float* __restrict__ ada, int sh_off, int sc_off, float* __restrict__ out){
  __shared__ float red[8];
  int tok = blockIdx.x;
  int b = tok >> 10;                 // S = 1024
  const float* xr = x + (size_t)tok*D_MODEL;
  int d0 = threadIdx.x*4;
  float4 v = *(const float4*)(xr + d0);
  float s  = v.x+v.y+v.z+v.w;
  float ss = v.x*v.x+v.y*v.y+v.z*v.z+v.w*v.w;
  #pragma unroll
  for (int off=32; off; off>>=1){ s += __shfl_xor(s,off); ss += __shfl_xor(ss,off); }
  int wave = threadIdx.x>>6, lane = threadIdx.x&63;
  if (lane==0){ red[wave]=s; red[4+wave]=ss; }
  __syncthreads();
  s  = red[0]+red[1]+red[2]+red[3];
  ss = red[4]+red[5]+red[6]+red[7];
  float mu  = s * (1.f/D_MODEL);
  float var = ss * (1.f/D_MODEL) - mu*mu;
  float rstd = rsqrtf(var + 1e-6f);
  const float* ar = ada + (size_t)b*(6*D_MODEL);
  float4 gv  = *(const float4*)(g   + d0);
  float4 bv  = *(const float4*)(bta + d0);
  float4 scv = *(const float4*)(ar + sc_off + d0);
  float4 shv = *(const float4*)(ar + sh_off + d0);
  float4 o;
  o.x = ((v.x-mu)*rstd*gv.x + bv.x)*(1.f+scv.x) + shv.x;
  o.y = ((v.y-mu)*rstd*gv.y + bv.y)*(1.f+scv.y) + shv.y;
  o.z = ((v.z-mu)*rstd*gv.z + bv.z)*(1.f+scv.z) + shv.z;
  o.w = ((v.w-mu)*rstd*gv.w + bv.w)*(1.f+scv.w) + shv.w;
  *(float4*)(out + (size_t)tok*D_MODEL + d0) = o;
}

// ---------------- generic fp32 GEMM: C[M,N] = A[M,K] @ B[K,N] (row-major) ----------------
// mode 0: C = acc ; mode 1: C = silu(aux) * acc  (elementwise aux read at same index)
__global__ __launch_bounds__(256) void gemm_kernel(
    const float* __restrict__ A, const float* __restrict__ B, float* __restrict__ C,
    int M, int N, int K, int mode, const float* __restrict__ aux){
  __shared__ float As[16][68];   // transposed A tile: As[k][m]
  __shared__ float Bs[16][68];   // Bs[k][n]
  int t  = threadIdx.x;
  int tx = t & 15, ty = t >> 4;
  int bm = blockIdx.y*64, bn = blockIdx.x*64;
  const float* Ab = A + (size_t)bm*K;
  const float* Bb = B + bn;
  float acc[4][4] = {{0,0,0,0},{0,0,0,0},{0,0,0,0},{0,0,0,0}};
  int arow = t >> 2, acol = (t & 3)*4;   // A tile: 64 rows x 16 k
  int brow = t >> 4, bcol = (t & 15)*4;  // B tile: 16 k  x 64 n
  for (int kt = 0; kt < K; kt += 16){
    float4 av = *(const float4*)(Ab + (size_t)arow*K + kt + acol);
    float4 bv = *(const float4*)(Bb + (size_t)(kt+brow)*N + bcol);
    __syncthreads();
    As[acol+0][arow]=av.x; As[acol+1][arow]=av.y; As[acol+2][arow]=av.z; As[acol+3][arow]=av.w;
    *(float4*)&Bs[brow][bcol] = bv;
    __syncthreads();
    #pragma unroll
    for (int kk=0; kk<16; kk++){
      float4 a4 = *(float4*)&As[kk][ty*4];
      float4 b4 = *(float4*)&Bs[kk][tx*4];
      acc[0][0]+=a4.x*b4.x; acc[0][1]+=a4.x*b4.y; acc[0][2]+=a4.x*b4.z; acc[0][3]+=a4.x*b4.w;
      acc[1][0]+=a4.y*b4.x; acc[1][1]+=a4.y*b4.y; acc[1][2]+=a4.y*b4.z; acc[1][3]+=a4.y*b4.w;
      acc[2][0]+=a4.z*b4.x; acc[2][1]+=a4.z*b4.y; acc[2][2]+=a4.z*b4.z; acc[2][3]+=a4.z*b4.w;
      acc[3][0]+=a4.w*b4.x; acc[3][1]+=a4.w*b4.y; acc[3][2]+=a4.w*b4.z; acc[3][3]+=a4.w*b4.w;
    }
  }
  int row0 = bm + ty*4, col0 = bn + tx*4;
  #pragma unroll
  for (int i=0;i<4;i++){
    size_t idx = (size_t)(row0+i)*N + col0;
    float4 r = make_float4(acc[i][0],acc[i][1],acc[i][2],acc[i][3]);
    if (mode==1){
      float4 hv = *(const float4*)(aux+idx);
      r.x *= silu_f(hv.x); r.y *= silu_f(hv.y); r.z *= silu_f(hv.z); r.w *= silu_f(hv.w);
    }
    *(float4*)(C+idx) = r;
  }
}

// ---------------- dense flash attention (grid: bias=-|q-k|, sem: bias=0) ----------------
// q,k,v,out layout: [B,S,D] with D index = h*64+d. grid: (S/16, H, B), 256 threads.
// mode 0 = grid (distance bias), mode 1 = sem (no bias)
__global__ __launch_bounds__(256) void flash_kernel(
    const float* __restrict__ q, const float* __restrict__ k, const float* __restrict__ v,
    float* __restrict__ out, int mode){
  __shared__ float Qs[16][68];
  __shared__ float Ks[64][68];
  __shared__ float Vs[64][68];
  __shared__ float Ps[16][68];
  int t = threadIdx.x;
  int b = blockIdx.z, h = blockIdx.y, q0 = blockIdx.x*16;
  const float* qb = q + ((size_t)b*SEQ + q0)*D_MODEL + h*DH;
  { // load Q tile: 16 rows x 16 float4
    int r = t >> 4, c = (t & 15)*4;
    *(float4*)&Qs[r][c] = *(const float4*)(qb + (size_t)r*D_MODEL + c);
  }
  int qi = t >> 4;   // 0..15 : query row within tile (also O row)
  int tx = t & 15;   // 0..15 : score k-group / O d-group
  int gq = q0 + qi;
  float m_run = -1e30f, l_run = 0.f;
  float o0=0.f, o1=0.f, o2=0.f, o3=0.f;
  __syncthreads();
  for (int kt = 0; kt < SEQ/64; kt++){
    int k0 = kt*64;
    const float* kb = k + ((size_t)b*SEQ + k0)*D_MODEL + h*DH;
    const float* vb = v + ((size_t)b*SEQ + k0)*D_MODEL + h*DH;
    __syncthreads();  // previous PV reads of Ks/Vs done
    #pragma unroll
    for (int i=0;i<4;i++){
      int idx = t + i*256;
      int r = idx >> 4, c = (idx & 15)*4;
      *(float4*)&Ks[r][c] = *(const float4*)(kb + (size_t)r*D_MODEL + c);
      *(float4*)&Vs[r][c] = *(const float4*)(vb + (size_t)r*D_MODEL + c);
    }
    __syncthreads();
    float sc[4];
    #pragma unroll
    for (int j=0;j<4;j++){
      int kk = tx + 16*j;
      float acc = 0.f;
      #pragma unroll
      for (int d=0; d<DH; d+=4){
        float4 qv = *(float4*)&Qs[qi][d];
        float4 kv = *(float4*)&Ks[kk][d];
        acc += qv.x*kv.x + qv.y*kv.y + qv.z*kv.z + qv.w*kv.w;
      }
      acc *= 0.125f;
      if (mode==0) acc -= fabsf((float)(gq - (k0+kk)));
      sc[j] = acc;
    }
    float mt = fmaxf(fmaxf(sc[0],sc[1]), fmaxf(sc[2],sc[3]));
    #pragma unroll
    for (int off=1; off<16; off<<=1) mt = fmaxf(mt, __shfl_xor(mt, off));
    float m_new = fmaxf(m_run, mt);
    float alpha = __expf(m_run - m_new);
    float psum = 0.f;
    #pragma unroll
    for (int j=0;j<4;j++){
      float p = __expf(sc[j] - m_new);
      Ps[qi][tx + 16*j] = p;
      psum += p;
    }
    #pragma unroll
    for (int off=1; off<16; off<<=1) psum += __shfl_xor(psum, off);
    l_run = l_run*alpha + psum;
    m_run = m_new;
    o0*=alpha; o1*=alpha; o2*=alpha; o3*=alpha;
    __syncthreads();  // Ps visible
    #pragma unroll 8
    for (int kk=0; kk<64; kk++){
      float p = Ps[qi][kk];
      float4 vv = *(float4*)&Vs[kk][tx*4];
      o0 += p*vv.x; o1 += p*vv.y; o2 += p*vv.z; o3 += p*vv.w;
    }
  }
  float inv = 1.f/l_run;
  float4 r = make_float4(o0*inv, o1*inv, o2*inv, o3*inv);
  *(float4*)(out + ((size_t)b*SEQ + gq)*D_MODEL + h*DH + tx*4) = r;
}

// ---------------- sparse attention: reg (k in {q-1,q,q+1}), ent (pair) ----------------
// masked entries have bias -1e9 -> exp underflows to 0 exactly; computing only allowed k is exact.
// One wave per (b,h,q); lane = d. mode 1 = reg, mode 2 = ent.
__global__ __launch_bounds__(256) void sparse_attn_kernel(
    const float* __restrict__ q, const float* __restrict__ k, const float* __restrict__ v,
    float* __restrict__ out, int mode){
  int wid  = (blockIdx.x * 256 + threadIdx.x) >> 6;
  int lane = threadIdx.x & 63;
  int qpos = wid & (SEQ-1);
  int h    = (wid >> 10) & (NHEAD-1);
  int b    = wid >> 14;
  const size_t base = ((size_t)b*SEQ)*D_MODEL + (size_t)h*DH;
  float qv = q[base + (size_t)qpos*D_MODEL + lane];
  int ks[3]; int nk = 0;
  if (mode == 1){
    if (qpos > 0) ks[nk++] = qpos-1;
    ks[nk++] = qpos;
    if (qpos < SEQ-1) ks[nk++] = qpos+1;
  } else {
    int k0 = qpos & ~1;
    ks[nk++] = k0; ks[nk++] = k0+1;
  }
  float sc[3], vl[3];
  for (int j=0;j<nk;j++){
    float kv = k[base + (size_t)ks[j]*D_MODEL + lane];
    float p = qv*kv;
    #pragma unroll
    for (int off=1; off<64; off<<=1) p += __shfl_xor(p, off);
    sc[j] = p * 0.125f;
    vl[j] = v[base + (size_t)ks[j]*D_MODEL + lane];
  }
  float m = sc[0];
  for (int j=1;j<nk;j++) m = fmaxf(m, sc[j]);
  float l = 0.f, o = 0.f;
  for (int j=0;j<nk;j++){
    float p = __expf(sc[j]-m);
    l += p; o += p*vl[j];
  }
  out[base + (size_t)qpos*D_MODEL + lane] = o / l;
}

// ---------------- fusion: gate = softmax([o1..o4]@wg + bg); fused = sum gate_i*o_i ----------------
__global__ __launch_bounds__(256) void fusion_kernel(
    const float* __restrict__ o1, const float* __restrict__ o2,
    const float* __restrict__ o3, const float* __restrict__ o4,
    const float* __restrict__ wg, const float* __restrict__ bg,
    float* __restrict__ fused){
  __shared__ float red[4][4];
  int tok = blockIdx.x;
  int d0 = threadIdx.x*4;
  size_t base = (size_t)tok*D_MODEL + d0;
  float4 a  = *(const float4*)(o1+base);
  float4 b4 = *(const float4*)(o2+base);
  float4 c4 = *(const float4*)(o3+base);
  float4 e4 = *(const float4*)(o4+base);
  float av[4] = {a.x,a.y,a.z,a.w};
  float bv[4] = {b4.x,b4.y,b4.z,b4.w};
  float cv[4] = {c4.x,c4.y,c4.z,c4.w};
  float ev[4] = {e4.x,e4.y,e4.z,e4.w};
  float lg[4] = {0,0,0,0};
  #pragma unroll
  for (int j=0;j<4;j++){
    int d = d0+j;
    float4 w0 = *(const float4*)(wg + (size_t)(0*D_MODEL+d)*4);
    float4 w1 = *(const float4*)(wg + (size_t)(1*D_MODEL+d)*4);
    float4 w2 = *(const float4*)(wg + (size_t)(2*D_MODEL+d)*4);
    float4 w3 = *(const float4*)(wg + (size_t)(3*D_MODEL+d)*4);
    lg[0] += av[j]*w0.x + bv[j]*w1.x + cv[j]*w2.x + ev[j]*w3.x;
    lg[1] += av[j]*w0.y + bv[j]*w1.y + cv[j]*w2.y + ev[j]*w3.y;
    lg[2] += av[j]*w0.z + bv[j]*w1.z + cv[j]*w2.z + ev[j]*w3.z;
    lg[3] += av[j]*w0.w + bv[j]*w1.w + cv[j]*w2.w + ev[j]*w3.w;
  }
  #pragma unroll
  for (int c=0;c<4;c++)
    #pragma unroll
    for (int off=32; off; off>>=1) lg[c] += __shfl_xor(lg[c], off);
  int wave = threadIdx.x>>6, lane = threadIdx.x&63;
  if (lane==0){ red[wave][0]=lg[0]; red[wave][1]=lg[1]; red[wave][2]=lg[2]; red[wave][3]=lg[3]; }
  __syncthreads();
  float logit[4];
  #pragma unroll
  for (int c=0;c<4;c++) logit[c] = red[0][c]+red[1][c]+red[2][c]+red[3][c] + bg[c];
  float m = fmaxf(fmaxf(logit[0],logit[1]), fmaxf(logit[2],logit[3]));
  float e0=__expf(logit[0]-m), e1=__expf(logit[1]-m), e2=__expf(logit[2]-m), e3=__expf(logit[3]-m);
  float inv = 1.f/(e0+e1+e2+e3);
  float g0=e0*inv, g1=e1*inv, g2=e2*inv, g3=e3*inv;
  float4 f;
  f.x = g0*a.x + g1*b4.x + g2*c4.x + g3*e4.x;
  f.y = g0*a.y + g1*b4.y + g2*c4.y + g3*e4.y;
  f.z = g0*a.z + g1*b4.z + g2*c4.z + g3*e4.z;
  f.w = g0*a.w + g1*b4.w + g2*c4.w + g3*e4.w;
  *(float4*)(fused+base) = f;
}

// ---------------- residual: out = xin + ada[b, g_off + d] * t ----------------
__global__ __launch_bounds__(256) void resid_kernel(
    const float* __restrict__ xin, const float* __restrict__ ada, int g_off,
    const float* __restrict__ t, float* __restrict__ out){
  size_t i = ((size_t)blockIdx.x*256 + threadIdx.x)*4;
  int b = (int)(i >> 20);           // S*D = 2^20 per batch
  int d = (int)(i & (D_MODEL-1));
  float4 xv = *(const float4*)(xin + i);
  float4 tv = *(const float4*)(t + i);
  float4 gv = *(const float4*)(ada + (size_t)b*(6*D_MODEL) + g_off + d);
  float4 o;
  o.x = xv.x + gv.x*tv.x;
  o.y = xv.y + gv.y*tv.y;
  o.z = xv.z + gv.z*tv.z;
  o.w = xv.w + gv.w*tv.w;
  *(float4*)(out + i) = o;
}

extern "C" void kernel_launch(void* const* d_in, const int* in_sizes, int n_in,
                              void* d_out, int out_size, void* d_ws, size_t ws_size,
                              hipStream_t stream){
  (void)in_sizes; (void)n_in; (void)out_size; (void)ws_size;
  const float* x      = (const float*)d_in[0];
  const float* t_emb  = (const float*)d_in[1];
  const float* ln1_g  = (const float*)d_in[2];
  const float* ln1_b  = (const float*)d_in[3];
  const float* ln2_g  = (const float*)d_in[4];
  const float* ln2_b  = (const float*)d_in[5];
  const float* ada_w  = (const float*)d_in[6];
  const float* ada_b  = (const float*)d_in[7];
  const float* fus_wg = (const float*)d_in[8];
  const float* fus_bg = (const float*)d_in[9];
  const float* fus_wo = (const float*)d_in[10];
  const float* ffn_w1 = (const float*)d_in[11];
  const float* ffn_w2 = (const float*)d_in[12];
  const float* ffn_w3 = (const float*)d_in[13];
  const float* aw[4][4];   // [branch][wq,wk,wv,wo], branches: grid,reg,ent,sem
  for (int p=0;p<4;p++)
    for (int w=0;w<4;w++)
      aw[p][w] = (const float*)d_in[14 + p*4 + w];

  char* ws = (char*)d_ws;
  const size_t SZ = (size_t)NTOK * D_MODEL * sizeof(float);  // 16 MiB per token-buffer
  float* nx   = (float*)(ws + 0*SZ);
  float* qb   = (float*)(ws + 1*SZ);
  float* kb   = (float*)(ws + 2*SZ);
  float* vb   = (float*)(ws + 3*SZ);
  float* ao   = (float*)(ws + 4*SZ);
  float* ob[4]= {(float*)(ws+5*SZ),(float*)(ws+6*SZ),(float*)(ws+7*SZ),(float*)(ws+8*SZ)};
  float* adab = (float*)(ws + 9*SZ);
  // After fusion, o1..o4 / q / k / v / ao are dead -> overlay:
  float* fused   = kb;                  // fusion output
  float* t1      = vb;                  // fused @ fus_wo
  float* x1      = qb;                  // first residual
  float* hbuf    = (float*)(ws + 5*SZ); // FFN hidden [4096,4096] overlays ob[0..3]
  float* ffn_out = ao;

  dim3 b256(256);
  // 1) AdaLN modulation vector
  ada_kernel<<<dim3(6*D_MODEL/256, BATCH), b256, 0, stream>>>(t_emb, ada_w, ada_b, adab);
  // 2) nx = modulated LN1(x)
  ln_mod_kernel<<<NTOK, b256, 0, stream>>>(x, ln1_g, ln1_b, adab, 0, D_MODEL, nx);
  // 3) four attention branches
  for (int p=0;p<4;p++){
    dim3 gproj(D_MODEL/64, NTOK/64);
    gemm_kernel<<<gproj, b256, 0, stream>>>(nx, aw[p][0], qb, NTOK, D_MODEL, D_MODEL, 0, nullptr);
    gemm_kernel<<<gproj, b256, 0, stream>>>(nx, aw[p][1], kb, NTOK, D_MODEL, D_MODEL, 0, nullptr);
    gemm_kernel<<<gproj, b256, 0, stream>>>(nx, aw[p][2], vb, NTOK, D_MODEL, D_MODEL, 0, nullptr);
    if (p == 0)
      flash_kernel<<<dim3(SEQ/16, NHEAD, BATCH), b256, 0, stream>>>(qb, kb, vb, ao, 0);
    else if (p == 3)
      flash_kernel<<<dim3(SEQ/16, NHEAD, BATCH), b256, 0, stream>>>(qb, kb, vb, ao, 1);
    else
      sparse_attn_kernel<<<dim3(BATCH*NHEAD*SEQ/4), b256, 0, stream>>>(qb, kb, vb, ao, p);
    gemm_kernel<<<gproj, b256, 0, stream>>>(ao, aw[p][3], ob[p], NTOK, D_MODEL, D_MODEL, 0, nullptr);
  }
  // 4) learned fusion gate
  fusion_kernel<<<NTOK, b256, 0, stream>>>(ob[0], ob[1], ob[2], ob[3], fus_wg, fus_bg, fused);
  // 5) t1 = fused @ fus_wo
  gemm_kernel<<<dim3(D_MODEL/64, NTOK/64), b256, 0, stream>>>(fused, fus_wo, t1, NTOK, D_MODEL, D_MODEL, 0, nullptr);
  // 6) x1 = x + g_m * t1
  resid_kernel<<<dim3(NTOK*D_MODEL/1024), b256, 0, stream>>>(x, adab, 2*D_MODEL, t1, x1);
  // 7) nx2 = modulated LN2(x1)
  ln_mod_kernel<<<NTOK, b256, 0, stream>>>(x1, ln2_g, ln2_b, adab, 3*D_MODEL, 4*D_MODEL, nx);
  // 8) h = nx2 @ w1
  gemm_kernel<<<dim3(FFDIM/64, NTOK/64), b256, 0, stream>>>(nx, ffn_w1, hbuf, NTOK, FFDIM, D_MODEL, 0, nullptr);
  // 9) h = silu(h) * (nx2 @ w3)   (epilogue reads h, writes h in place)
  gemm_kernel<<<dim3(FFDIM/64, NTOK/64), b256, 0, stream>>>(nx, ffn_w3, hbuf, NTOK, FFDIM, D_MODEL, 1, hbuf);
  // 10) ffn_out = h @ w2
  gemm_kernel<<<dim3(D_MODEL/64, NTOK/64), b256, 0, stream>>>(hbuf, ffn_w2, ffn_out, NTOK, D_MODEL, FFDIM, 0, nullptr);
  // 11) out = x1 + g_f * ffn_out
  resid_kernel<<<dim3(NTOK*D_MODEL/1024), b256, 0, stream>>>(x1, adab, 5*D_MODEL, ffn_out, (float*)d_out);
}

// Round 2
// 1806.185 us; speedup vs baseline: 2.7995x; 2.7995x over previous
//
#include <hip/hip_runtime.h>
#include <cstddef>
#include <cstdint>

// (B,S,D,H,F) = (4,1024,1024,16,4096)
#define D_MODEL 1024
#define SEQ     1024
#define BATCH   4
#define NHEAD   16
#define DH      64
#define FFDIM   4096
#define NTOK    4096
#define QKV_LD  12288   // 4 branches x (q,k,v) x 1024

typedef unsigned short u16;
typedef __bf16 bf16x8 __attribute__((ext_vector_type(8)));
typedef float  f32x4  __attribute__((ext_vector_type(4)));

__device__ __forceinline__ u16 f2b(float f){
  unsigned u = __builtin_bit_cast(unsigned, f);
  u += 0x7FFFu + ((u >> 16) & 1u);          // RNE
  return (u16)(u >> 16);
}
__device__ __forceinline__ float b2f(unsigned h){
  unsigned u = (h & 0xffffu) << 16;
  return __builtin_bit_cast(float, u);
}
__device__ __forceinline__ float silu_f(float x){ return x / (1.f + __expf(-x)); }

__device__ __forceinline__ void async16(const u16* g, u16* l){
  __builtin_amdgcn_global_load_lds((__attribute__((address_space(1))) void*)(g),
                                   (__attribute__((address_space(3))) void*)(l), 16, 0, 0);
}

// ---------------- weight transpose+convert: src fp32 [K,N] -> dst bf16 [N,K] ----------------
struct Ptrs { const float* p[17]; };
__global__ __launch_bounds__(256) void transpose_cvt(Ptrs ps, u16* __restrict__ dst, int K, int N){
  __shared__ float tile[32][33];
  const float* __restrict__ src = ps.p[blockIdx.z];
  u16* d = dst + (size_t)blockIdx.z * K * N;
  int n0 = blockIdx.x*32, k0 = blockIdx.y*32;
  int tx = threadIdx.x & 31, ty = threadIdx.x >> 5;
  #pragma unroll
  for (int i=0;i<4;i++){ int kk = ty + i*8; tile[kk][tx] = src[(size_t)(k0+kk)*N + n0+tx]; }
  __syncthreads();
  #pragma unroll
  for (int i=0;i<4;i++){ int nn = ty + i*8; d[(size_t)(n0+nn)*K + k0+tx] = f2b(tile[tx][nn]); }
}

// ---------------- ada = silu(t_emb) @ ada_w + ada_b  -> [B, 6D] fp32 ----------------
__global__ __launch_bounds__(256) void ada_kernel(
    const float* __restrict__ t_emb, const float* __restrict__ W,
    const float* __restrict__ bias, float* __restrict__ out){
  __shared__ float st[D_MODEL];
  int b = blockIdx.y;
  for (int i = threadIdx.x; i < D_MODEL; i += 256) st[i] = silu_f(t_emb[b*D_MODEL + i]);
  __syncthreads();
  int n = blockIdx.x*256 + threadIdx.x;
  float acc = bias[n];
  for (int k = 0; k < D_MODEL; ++k) acc += st[k] * W[(size_t)k*(6*D_MODEL) + n];
  out[(size_t)b*(6*D_MODEL) + n] = acc;
}

// ---------------- nx = (ln(x)*g+b)*(1+sc)+sh -> bf16 ----------------
__global__ __launch_bounds__(256) void ln_mod_kernel(
    const float* __restrict__ x, const float* __restrict__ g, const float* __restrict__ bta,
    const float* __restrict__ ada, int sh_off, int sc_off, u16* __restrict__ out){
  __shared__ float red[8];
  int tok = blockIdx.x;
  int b = tok >> 10;
  const float* xr = x + (size_t)tok*D_MODEL;
  int d0 = threadIdx.x*4;
  float4 v = *(const float4*)(xr + d0);
  float s  = v.x+v.y+v.z+v.w;
  float ss = v.x*v.x+v.y*v.y+v.z*v.z+v.w*v.w;
  #pragma unroll
  for (int off=32; off; off>>=1){ s += __shfl_xor(s,off); ss += __shfl_xor(ss,off); }
  int wave = threadIdx.x>>6, lane = threadIdx.x&63;
  if (lane==0){ red[wave]=s; red[4+wave]=ss; }
  __syncthreads();
  s  = red[0]+red[1]+red[2]+red[3];
  ss = red[4]+red[5]+red[6]+red[7];
  float mu  = s * (1.f/D_MODEL);
  float var = ss * (1.f/D_MODEL) - mu*mu;
  float rstd = rsqrtf(var + 1e-6f);
  const float* ar = ada + (size_t)b*(6*D_MODEL);
  float4 gv  = *(const float4*)(g   + d0);
  float4 bv  = *(const float4*)(bta + d0);
  float4 scv = *(const float4*)(ar + sc_off + d0);
  float4 shv = *(const float4*)(ar + sh_off + d0);
  float o0 = ((v.x-mu)*rstd*gv.x + bv.x)*(1.f+scv.x) + shv.x;
  float o1 = ((v.y-mu)*rstd*gv.y + bv.y)*(1.f+scv.y) + shv.y;
  float o2 = ((v.z-mu)*rstd*gv.z + bv.z)*(1.f+scv.z) + shv.z;
  float o3 = ((v.w-mu)*rstd*gv.w + bv.w)*(1.f+scv.w) + shv.w;
  uint2 o;
  o.x = (unsigned)f2b(o0) | ((unsigned)f2b(o1) << 16);
  o.y = (unsigned)f2b(o2) | ((unsigned)f2b(o3) << 16);
  *(uint2*)(out + (size_t)tok*D_MODEL + d0) = o;
}

// ---------------- bf16 MFMA GEMM: C[M,N] = A[M,K] @ BT[N,K]^T ----------------
// 128x128 tile, BK=32, 4 waves each computing a 64x64 quadrant via 4x4 MFMA tiles.
// mode 0: v = acc ; mode 1: v = silu(aux[idx]) * acc. Writes Cf (fp32) and/or Cb (bf16).
__global__ __launch_bounds__(256) void gemm_bf16(
    const u16* __restrict__ A, const u16* __restrict__ B,
    float* __restrict__ Cf, u16* __restrict__ Cb,
    int M, int N, int K, const float* __restrict__ aux, int mode,
    long sAz, long sBz, long sCz){
  __shared__ u16 As[128*32];
  __shared__ u16 Bs[128*32];
  int z = blockIdx.z;
  A += (size_t)z * sAz;  B += (size_t)z * sBz;
  size_t cz = (size_t)z * sCz;
  int t = threadIdx.x, w = t >> 6, lane = t & 63;
  int bm = blockIdx.y*128, bn = blockIdx.x*128;
  int srow = lane >> 2, scol = (lane & 3)*8;
  const u16* Ag0 = A + (size_t)(bm + (w*2+0)*16 + srow)*K + scol;
  const u16* Ag1 = A + (size_t)(bm + (w*2+1)*16 + srow)*K + scol;
  const u16* Bg0 = B + (size_t)(bn + (w*2+0)*16 + srow)*K + scol;
  const u16* Bg1 = B + (size_t)(bn + (w*2+1)*16 + srow)*K + scol;
  u16* Al0 = As + (w*2+0)*512;
  u16* Al1 = As + (w*2+1)*512;
  u16* Bl0 = Bs + (w*2+0)*512;
  u16* Bl1 = Bs + (w*2+1)*512;
  int m16 = lane & 15, q8 = (lane >> 4)*8;
  int RO = (w >> 1)*64, CO = (w & 1)*64;
  f32x4 acc[4][4];
  f32x4 zz = {0.f,0.f,0.f,0.f};
  #pragma unroll
  for (int mi=0;mi<4;mi++)
    #pragma unroll
    for (int ni=0;ni<4;ni++) acc[mi][ni] = zz;
  for (int kt = 0; kt < K; kt += 32){
    __syncthreads();
    async16(Ag0, Al0); async16(Ag1, Al1);
    async16(Bg0, Bl0); async16(Bg1, Bl1);
    Ag0 += 32; Ag1 += 32; Bg0 += 32; Bg1 += 32;
    __syncthreads();
    bf16x8 af[4], bfr[4];
    #pragma unroll
    for (int mi=0;mi<4;mi++) af[mi]  = *(const bf16x8*)(As + (RO + mi*16 + m16)*32 + q8);
    #pragma unroll
    for (int ni=0;ni<4;ni++) bfr[ni] = *(const bf16x8*)(Bs + (CO + ni*16 + m16)*32 + q8);
    #pragma unroll
    for (int mi=0;mi<4;mi++)
      #pragma unroll
      for (int ni=0;ni<4;ni++)
        acc[mi][ni] = __builtin_amdgcn_mfma_f32_16x16x32_bf16(af[mi], bfr[ni], acc[mi][ni], 0,0,0);
  }
  int er = (lane >> 4)*4;
  #pragma unroll
  for (int mi=0;mi<4;mi++){
    #pragma unroll
    for (int ni=0;ni<4;ni++){
      #pragma unroll
      for (int r=0;r<4;r++){
        int m = bm + RO + mi*16 + er + r;
        int n = bn + CO + ni*16 + m16;
        size_t idx = cz + (size_t)m*N + n;
        float v = acc[mi][ni][r];
        if (mode == 1) v *= silu_f(aux[idx]);
        if (Cf) Cf[idx] = v;
        if (Cb) Cb[idx] = f2b(v);
      }
    }
  }
}

// ---------------- dense flash attention, bf16 in/out, fp32 math ----------------
// q,k,v row stride QKV_LD; out row stride D_MODEL. mode 0 = grid bias -|q-k|, 1 = none.
__global__ __launch_bounds__(256) void flash_kernel(
    const u16* __restrict__ q, const u16* __restrict__ k, const u16* __restrict__ v,
    u16* __restrict__ out, int mode){
  __shared__ float Qs[16][68];
  __shared__ float Ks[64][68];
  __shared__ float Vs[64][68];
  __shared__ float Ps[16][68];
  int t = threadIdx.x;
  int b = blockIdx.z, h = blockIdx.y, q0 = blockIdx.x*16;
  const u16* qb = q + ((size_t)b*SEQ + q0)*QKV_LD + h*DH;
  { int r = t >> 4, c = (t & 15)*4;
    uint2 raw = *(const uint2*)(qb + (size_t)r*QKV_LD + c);
    Qs[r][c+0]=b2f(raw.x); Qs[r][c+1]=b2f(raw.x>>16);
    Qs[r][c+2]=b2f(raw.y); Qs[r][c+3]=b2f(raw.y>>16); }
  int qi = t >> 4, tx = t & 15;
  int gq = q0 + qi;
  float m_run = -1e30f, l_run = 0.f;
  float o0=0.f, o1=0.f, o2=0.f, o3=0.f;
  __syncthreads();
  for (int kt = 0; kt < SEQ/64; kt++){
    int k0 = kt*64;
    const u16* kb = k + ((size_t)b*SEQ + k0)*QKV_LD + h*DH;
    const u16* vb = v + ((size_t)b*SEQ + k0)*QKV_LD + h*DH;
    __syncthreads();
    #pragma unroll
    for (int i=0;i<4;i++){
      int idx = t + i*256;
      int r = idx >> 4, c = (idx & 15)*4;
      uint2 kr = *(const uint2*)(kb + (size_t)r*QKV_LD + c);
      uint2 vr = *(const uint2*)(vb + (size_t)r*QKV_LD + c);
      Ks[r][c+0]=b2f(kr.x); Ks[r][c+1]=b2f(kr.x>>16); Ks[r][c+2]=b2f(kr.y); Ks[r][c+3]=b2f(kr.y>>16);
      Vs[r][c+0]=b2f(vr.x); Vs[r][c+1]=b2f(vr.x>>16); Vs[r][c+2]=b2f(vr.y); Vs[r][c+3]=b2f(vr.y>>16);
    }
    __syncthreads();
    float sc[4];
    #pragma unroll
    for (int j=0;j<4;j++){
      int kk = tx + 16*j;
      float acc = 0.f;
      #pragma unroll
      for (int d=0; d<DH; d+=4){
        float4 qv = *(float4*)&Qs[qi][d];
        float4 kv = *(float4*)&Ks[kk][d];
        acc += qv.x*kv.x + qv.y*kv.y + qv.z*kv.z + qv.w*kv.w;
      }
      acc *= 0.125f;
      if (mode==0) acc -= fabsf((float)(gq - (k0+kk)));
      sc[j] = acc;
    }
    float mt = fmaxf(fmaxf(sc[0],sc[1]), fmaxf(sc[2],sc[3]));
    #pragma unroll
    for (int off=1; off<16; off<<=1) mt = fmaxf(mt, __shfl_xor(mt, off));
    float m_new = fmaxf(m_run, mt);
    float alpha = __expf(m_run - m_new);
    float psum = 0.f;
    #pragma unroll
    for (int j=0;j<4;j++){
      float p = __expf(sc[j] - m_new);
      Ps[qi][tx + 16*j] = p;
      psum += p;
    }
    #pragma unroll
    for (int off=1; off<16; off<<=1) psum += __shfl_xor(psum, off);
    l_run = l_run*alpha + psum;
    m_run = m_new;
    o0*=alpha; o1*=alpha; o2*=alpha; o3*=alpha;
    __syncthreads();
    #pragma unroll 8
    for (int kk=0; kk<64; kk++){
      float p = Ps[qi][kk];
      float4 vv = *(float4*)&Vs[kk][tx*4];
      o0 += p*vv.x; o1 += p*vv.y; o2 += p*vv.z; o3 += p*vv.w;
    }
  }
  float inv = 1.f/l_run;
  uint2 o;
  o.x = (unsigned)f2b(o0*inv) | ((unsigned)f2b(o1*inv) << 16);
  o.y = (unsigned)f2b(o2*inv) | ((unsigned)f2b(o3*inv) << 16);
  *(uint2*)(out + ((size_t)b*SEQ + gq)*D_MODEL + h*DH + tx*4) = o;
}

// ---------------- sparse attention: reg (k in {q-1,q,q+1}) mode 1, ent (pair) mode 2 ----------------
__global__ __launch_bounds__(256) void sparse_attn_kernel(
    const u16* __restrict__ q, const u16* __restrict__ k, const u16* __restrict__ v,
    u16* __restrict__ out, int mode){
  int wid  = (blockIdx.x * 256 + threadIdx.x) >> 6;
  int lane = threadIdx.x & 63;
  int qpos = wid & (SEQ-1);
  int h    = (wid >> 10) & (NHEAD-1);
  int b    = wid >> 14;
  const size_t rbase = (size_t)b*SEQ*QKV_LD + (size_t)h*DH;
  float qv = b2f(q[rbase + (size_t)qpos*QKV_LD + lane]);
  int ks[3]; int nk = 0;
  if (mode == 1){
    if (qpos > 0) ks[nk++] = qpos-1;
    ks[nk++] = qpos;
    if (qpos < SEQ-1) ks[nk++] = qpos+1;
  } else {
    int k0 = qpos & ~1;
    ks[nk++] = k0; ks[nk++] = k0+1;
  }
  float sc[3], vl[3];
  for (int j=0;j<nk;j++){
    float kv = b2f(k[rbase + (size_t)ks[j]*QKV_LD + lane]);
    float p = qv*kv;
    #pragma unroll
    for (int off=1; off<64; off<<=1) p += __shfl_xor(p, off);
    sc[j] = p * 0.125f;
    vl[j] = b2f(v[rbase + (size_t)ks[j]*QKV_LD + lane]);
  }
  float m = sc[0];
  for (int j=1;j<nk;j++) m = fmaxf(m, sc[j]);
  float l = 0.f, o = 0.f;
  for (int j=0;j<nk;j++){
    float p = __expf(sc[j]-m);
    l += p; o += p*vl[j];
  }
  out[((size_t)b*SEQ + qpos)*D_MODEL + (size_t)h*DH + lane] = f2b(o / l);
}

// ---------------- fusion gate over bf16 branch outputs ----------------
__global__ __launch_bounds__(256) void fusion_kernel(
    const u16* __restrict__ o1, const u16* __restrict__ o2,
    const u16* __restrict__ o3, const u16* __restrict__ o4,
    const float* __restrict__ wg, const float* __restrict__ bg,
    u16* __restrict__ fused){
  __shared__ float red[4][4];
  int tok = blockIdx.x;
  int d0 = threadIdx.x*4;
  size_t base = (size_t)tok*D_MODEL + d0;
  uint2 ra = *(const uint2*)(o1+base);
  uint2 rb = *(const uint2*)(o2+base);
  uint2 rc = *(const uint2*)(o3+base);
  uint2 re = *(const uint2*)(o4+base);
  float av[4] = {b2f(ra.x), b2f(ra.x>>16), b2f(ra.y), b2f(ra.y>>16)};
  float bv[4] = {b2f(rb.x), b2f(rb.x>>16), b2f(rb.y), b2f(rb.y>>16)};
  float cv[4] = {b2f(rc.x), b2f(rc.x>>16), b2f(rc.y), b2f(rc.y>>16)};
  float ev[4] = {b2f(re.x), b2f(re.x>>16), b2f(re.y), b2f(re.y>>16)};
  float lg[4] = {0,0,0,0};
  #pragma unroll
  for (int j=0;j<4;j++){
    int d = d0+j;
    float4 w0 = *(const float4*)(wg + (size_t)(0*D_MODEL+d)*4);
    float4 w1 = *(const float4*)(wg + (size_t)(1*D_MODEL+d)*4);
    float4 w2 = *(const float4*)(wg + (size_t)(2*D_MODEL+d)*4);
    float4 w3 = *(const float4*)(wg + (size_t)(3*D_MODEL+d)*4);
    lg[0] += av[j]*w0.x + bv[j]*w1.x + cv[j]*w2.x + ev[j]*w3.x;
    lg[1] += av[j]*w0.y + bv[j]*w1.y + cv[j]*w2.y + ev[j]*w3.y;
    lg[2] += av[j]*w0.z + bv[j]*w1.z + cv[j]*w2.z + ev[j]*w3.z;
    lg[3] += av[j]*w0.w + bv[j]*w1.w + cv[j]*w2.w + ev[j]*w3.w;
  }
  #pragma unroll
  for (int c=0;c<4;c++)
    #pragma unroll
    for (int off=32; off; off>>=1) lg[c] += __shfl_xor(lg[c], off);
  int wave = threadIdx.x>>6, lane = threadIdx.x&63;
  if (lane==0){ red[wave][0]=lg[0]; red[wave][1]=lg[1]; red[wave][2]=lg[2]; red[wave][3]=lg[3]; }
  __syncthreads();
  float logit[4];
  #pragma unroll
  for (int c=0;c<4;c++) logit[c] = red[0][c]+red[1][c]+red[2][c]+red[3][c] + bg[c];
  float m = fmaxf(fmaxf(logit[0],logit[1]), fmaxf(logit[2],logit[3]));
  float e0=__expf(logit[0]-m), e1=__expf(logit[1]-m), e2=__expf(logit[2]-m), e3=__expf(logit[3]-m);
  float inv = 1.f/(e0+e1+e2+e3);
  float g0=e0*inv, g1=e1*inv, g2=e2*inv, g3=e3*inv;
  float f0 = g0*av[0] + g1*bv[0] + g2*cv[0] + g3*ev[0];
  float f1 = g0*av[1] + g1*bv[1] + g2*cv[1] + g3*ev[1];
  float f2 = g0*av[2] + g1*bv[2] + g2*cv[2] + g3*ev[2];
  float f3 = g0*av[3] + g1*bv[3] + g2*cv[3] + g3*ev[3];
  uint2 o;
  o.x = (unsigned)f2b(f0) | ((unsigned)f2b(f1) << 16);
  o.y = (unsigned)f2b(f2) | ((unsigned)f2b(f3) << 16);
  *(uint2*)(fused+base) = o;
}

// ---------------- residual: out = xin + ada[b, g_off + d] * t ----------------
__global__ __launch_bounds__(256) void resid_kernel(
    const float* __restrict__ xin, const float* __restrict__ ada, int g_off,
    const float* __restrict__ t, float* __restrict__ out){
  size_t i = ((size_t)blockIdx.x*256 + threadIdx.x)*4;
  int b = (int)(i >> 20);
  int d = (int)(i & (D_MODEL-1));
  float4 xv = *(const float4*)(xin + i);
  float4 tv = *(const float4*)(t + i);
  float4 gv = *(const float4*)(ada + (size_t)b*(6*D_MODEL) + g_off + d);
  float4 o;
  o.x = xv.x + gv.x*tv.x;
  o.y = xv.y + gv.y*tv.y;
  o.z = xv.z + gv.z*tv.z;
  o.w = xv.w + gv.w*tv.w;
  *(float4*)(out + i) = o;
}

extern "C" void kernel_launch(void* const* d_in, const int* in_sizes, int n_in,
                              void* d_out, int out_size, void* d_ws, size_t ws_size,
                              hipStream_t stream){
  (void)in_sizes; (void)n_in; (void)out_size; (void)ws_size;
  const float* x      = (const float*)d_in[0];
  const float* t_emb  = (const float*)d_in[1];
  const float* ln1_g  = (const float*)d_in[2];
  const float* ln1_b  = (const float*)d_in[3];
  const float* ln2_g  = (const float*)d_in[4];
  const float* ln2_b  = (const float*)d_in[5];
  const float* ada_w  = (const float*)d_in[6];
  const float* ada_b  = (const float*)d_in[7];
  const float* fus_wg = (const float*)d_in[8];
  const float* fus_bg = (const float*)d_in[9];
  const float* fus_wo = (const float*)d_in[10];
  const float* ffn_w1 = (const float*)d_in[11];
  const float* ffn_w2 = (const float*)d_in[12];
  const float* ffn_w3 = (const float*)d_in[13];
  const float* aw[4][4];
  for (int p=0;p<4;p++)
    for (int w=0;w<4;w++)
      aw[p][w] = (const float*)d_in[14 + p*4 + w];

  const size_t MB = 1u<<20;
  char* ws = (char*)d_ws;
  u16*   WSQ  = (u16*)(ws);              // 17 x [1024,1024] bf16 = 34MB (qkv 0..11, wo 12..15, fus 16)
  u16*   W13  = (u16*)(ws + 34*MB);      // w1T, w3T [4096,1024] x2 = 16MB
  u16*   W2T  = (u16*)(ws + 50*MB);      // w2T [1024,4096] = 8MB
  u16*   NX   = (u16*)(ws + 58*MB);      // nx / nx2 bf16 = 8MB
  u16*   QKVb = (u16*)(ws + 66*MB);      // [4096,12288] bf16 = 96MB
  float* G1   = (float*)(ws + 66*MB);    //   overlay after attn: [4096,4096] fp32 = 64MB
  u16*   H    = (u16*)(ws + 130*MB);     //   overlay: [4096,4096] bf16 = 32MB
  u16*   AO   = (u16*)(ws + 166*MB);     // [4][4096,1024] bf16 = 32MB
  u16*   FUSED= (u16*)(ws + 166*MB);     //   overlay after wo-GEMM: 8MB
  float* T1   = (float*)(ws + 174*MB);   //   overlay: 16MB (also FFN_OUT)
  u16*   OB   = (u16*)(ws + 198*MB);     // [4][4096,1024] bf16 = 32MB
  float* X1   = (float*)(ws + 230*MB);   // 16MB
  float* ADAB = (float*)(ws + 246*MB);   // [4,6144] fp32

  u16* WOW  = WSQ + (size_t)12*1024*1024;
  u16* FUSW = WSQ + (size_t)16*1024*1024;
  u16* W3T  = W13 + (size_t)4096*1024;

  dim3 b256(256);
  // 0) weight convert+transpose
  Ptrs psq{};
  for (int p=0;p<4;p++) for (int w2=0;w2<3;w2++) psq.p[p*3+w2] = aw[p][w2];
  for (int p=0;p<4;p++) psq.p[12+p] = aw[p][3];
  psq.p[16] = fus_wo;
  transpose_cvt<<<dim3(32,32,17), b256, 0, stream>>>(psq, WSQ, 1024, 1024);
  Ptrs p13{}; p13.p[0]=ffn_w1; p13.p[1]=ffn_w3;
  transpose_cvt<<<dim3(128,32,2), b256, 0, stream>>>(p13, W13, 1024, 4096);
  Ptrs p2{}; p2.p[0]=ffn_w2;
  transpose_cvt<<<dim3(32,128,1), b256, 0, stream>>>(p2, W2T, 4096, 1024);

  // 1) ada + ln1
  ada_kernel<<<dim3(6*D_MODEL/256, BATCH), b256, 0, stream>>>(t_emb, ada_w, ada_b, ADAB);
  ln_mod_kernel<<<NTOK, b256, 0, stream>>>(x, ln1_g, ln1_b, ADAB, 0, D_MODEL, NX);

  // 2) all QKV projections in one GEMM: [4096,1024] @ [12288,1024]^T -> bf16 [4096,12288]
  gemm_bf16<<<dim3(QKV_LD/128, NTOK/128, 1), b256, 0, stream>>>(
      NX, WSQ, nullptr, QKVb, NTOK, QKV_LD, 1024, nullptr, 0, 0,0,0);

  // 3) attention branches -> AO[p]
  for (int p=0;p<4;p++){
    const u16* qp = QKVb + p*3072;
    const u16* kp = qp + 1024;
    const u16* vp = qp + 2048;
    u16* aop = AO + (size_t)p*NTOK*D_MODEL;
    if (p==0)
      flash_kernel<<<dim3(SEQ/16, NHEAD, BATCH), b256, 0, stream>>>(qp, kp, vp, aop, 0);
    else if (p==3)
      flash_kernel<<<dim3(SEQ/16, NHEAD, BATCH), b256, 0, stream>>>(qp, kp, vp, aop, 1);
    else
      sparse_attn_kernel<<<dim3(BATCH*NHEAD*SEQ/4), b256, 0, stream>>>(qp, kp, vp, aop, p);
  }

  // 4) batched output projections: OB[p] = AO[p] @ wo_p
  gemm_bf16<<<dim3(1024/128, NTOK/128, 4), b256, 0, stream>>>(
      AO, WOW, nullptr, OB, NTOK, 1024, 1024, nullptr, 0,
      (long)NTOK*1024, (long)1024*1024, (long)NTOK*1024);

  // 5) fusion gate
  fusion_kernel<<<NTOK, b256, 0, stream>>>(
      OB, OB + (size_t)NTOK*D_MODEL, OB + (size_t)2*NTOK*D_MODEL, OB + (size_t)3*NTOK*D_MODEL,
      fus_wg, fus_bg, FUSED);

  // 6) t1 = fused @ fus_wo (fp32)
  gemm_bf16<<<dim3(1024/128, NTOK/128, 1), b256, 0, stream>>>(
      FUSED, FUSW, T1, nullptr, NTOK, 1024, 1024, nullptr, 0, 0,0,0);

  // 7) x1 = x + g_m * t1
  resid_kernel<<<dim3(NTOK*D_MODEL/1024), b256, 0, stream>>>(x, ADAB, 2*D_MODEL, T1, X1);

  // 8) nx2 = modulated LN2(x1)
  ln_mod_kernel<<<NTOK, b256, 0, stream>>>(X1, ln2_g, ln2_b, ADAB, 3*D_MODEL, 4*D_MODEL, NX);

  // 9) G1 = nx2 @ w1 (fp32)
  gemm_bf16<<<dim3(FFDIM/128, NTOK/128, 1), b256, 0, stream>>>(
      NX, W13, G1, nullptr, NTOK, FFDIM, 1024, nullptr, 0, 0,0,0);

  // 10) H = silu(G1) * (nx2 @ w3)  (bf16)
  gemm_bf16<<<dim3(FFDIM/128, NTOK/128, 1), b256, 0, stream>>>(
      NX, W3T, nullptr, H, NTOK, FFDIM, 1024, G1, 1, 0,0,0);

  // 11) ffn_out = H @ w2 (fp32, reuse T1)
  gemm_bf16<<<dim3(1024/128, NTOK/128, 1), b256, 0, stream>>>(
      H, W2T, T1, nullptr, NTOK, 1024, FFDIM, nullptr, 0, 0,0,0);

  // 12) out = x1 + g_f * ffn_out
  resid_kernel<<<dim3(NTOK*D_MODEL/1024), b256, 0, stream>>>(X1, ADAB, 5*D_MODEL, T1, (float*)d_out);
}

// Round 4
// 1224.204 us; speedup vs baseline: 4.1303x; 1.4754x over previous
//
#include <hip/hip_runtime.h>
#include <cstddef>
#include <cstdint>

// (B,S,D,H,F) = (4,1024,1024,16,4096)
#define D_MODEL 1024
#define SEQ     1024
#define BATCH   4
#define NHEAD   16
#define DH      64
#define FFDIM   4096
#define NTOK    4096
#define QKV_LD  12288   // 4 branches x (q,k,v) x 1024

typedef unsigned short u16;
typedef __bf16 bf16x8 __attribute__((ext_vector_type(8)));
typedef float  f32x4  __attribute__((ext_vector_type(4)));

__device__ __forceinline__ u16 f2b(float f){
  unsigned u = __builtin_bit_cast(unsigned, f);
  u += 0x7FFFu + ((u >> 16) & 1u);          // RNE
  return (u16)(u >> 16);
}
__device__ __forceinline__ float b2f(unsigned h){
  unsigned u = (h & 0xffffu) << 16;
  return __builtin_bit_cast(float, u);
}
__device__ __forceinline__ float silu_f(float x){ return x / (1.f + __expf(-x)); }

__device__ __forceinline__ void async16(const u16* g, u16* l){
  __builtin_amdgcn_global_load_lds((__attribute__((address_space(1))) void*)(g),
                                   (__attribute__((address_space(3))) void*)(l), 16, 0, 0);
}

// ---------------- weight transpose+convert: src fp32 [K,N] -> dst bf16 [N,K] ----------------
struct Ptrs { const float* p[17]; };
__global__ __launch_bounds__(256) void transpose_cvt(Ptrs ps, u16* __restrict__ dst, int K, int N){
  __shared__ float tile[32][33];
  const float* __restrict__ src = ps.p[blockIdx.z];
  u16* d = dst + (size_t)blockIdx.z * K * N;
  int n0 = blockIdx.x*32, k0 = blockIdx.y*32;
  int tx = threadIdx.x & 31, ty = threadIdx.x >> 5;
  #pragma unroll
  for (int i=0;i<4;i++){ int kk = ty + i*8; tile[kk][tx] = src[(size_t)(k0+kk)*N + n0+tx]; }
  __syncthreads();
  #pragma unroll
  for (int i=0;i<4;i++){ int nn = ty + i*8; d[(size_t)(n0+nn)*K + k0+tx] = f2b(tile[tx][nn]); }
}

// ---------------- V pre-transpose for dense branches: Vt[branch2][b*16+h][d][s] bf16 ----------------
__global__ __launch_bounds__(256) void transpose_v(const u16* __restrict__ qkv, u16* __restrict__ vt){
  __shared__ u16 tile[64][72];
  int s0 = blockIdx.x*64;
  int bh = blockIdx.y;          // b*16+h
  int p2 = blockIdx.z;          // 0 -> branch 0 (grid), 1 -> branch 3 (sem)
  int p  = p2 ? 3 : 0;
  int b = bh >> 4, h = bh & 15;
  const u16* src = qkv + (size_t)b*SEQ*QKV_LD + p*3072 + 2048 + h*64;
  int t = threadIdx.x;
  int r = t >> 3, c8 = (t & 7)*8;
  #pragma unroll
  for (int i=0;i<2;i++){
    int s = r + i*32;
    *(uint4*)&tile[s][c8] = *(const uint4*)(src + (size_t)(s0+s)*QKV_LD + c8);
  }
  __syncthreads();
  u16* dst = vt + ((size_t)p2*64 + bh)*DH*SEQ;
  #pragma unroll
  for (int i=0;i<2;i++){
    int d = r + i*32;
    u16 tmp[8];
    #pragma unroll
    for (int j=0;j<8;j++) tmp[j] = tile[c8+j][d];
    *(uint4*)(dst + (size_t)d*SEQ + s0 + c8) = *(uint4*)tmp;
  }
}

// ---------------- ada = silu(t_emb) @ ada_w + ada_b  -> [B, 6D] fp32 ----------------
__global__ __launch_bounds__(256) void ada_kernel(
    const float* __restrict__ t_emb, const float* __restrict__ W,
    const float* __restrict__ bias, float* __restrict__ out){
  __shared__ float st[D_MODEL];
  int b = blockIdx.y;
  for (int i = threadIdx.x; i < D_MODEL; i += 256) st[i] = silu_f(t_emb[b*D_MODEL + i]);
  __syncthreads();
  int n = blockIdx.x*256 + threadIdx.x;
  float acc = bias[n];
  for (int k = 0; k < D_MODEL; ++k) acc += st[k] * W[(size_t)k*(6*D_MODEL) + n];
  out[(size_t)b*(6*D_MODEL) + n] = acc;
}

// ---------------- nx = (ln(x)*g+b)*(1+sc)+sh -> bf16 ----------------
__global__ __launch_bounds__(256) void ln_mod_kernel(
    const float* __restrict__ x, const float* __restrict__ g, const float* __restrict__ bta,
    const float* __restrict__ ada, int sh_off, int sc_off, u16* __restrict__ out){
  __shared__ float red[8];
  int tok = blockIdx.x;
  int b = tok >> 10;
  const float* xr = x + (size_t)tok*D_MODEL;
  int d0 = threadIdx.x*4;
  float4 v = *(const float4*)(xr + d0);
  float s  = v.x+v.y+v.z+v.w;
  float ss = v.x*v.x+v.y*v.y+v.z*v.z+v.w*v.w;
  #pragma unroll
  for (int off=32; off; off>>=1){ s += __shfl_xor(s,off); ss += __shfl_xor(ss,off); }
  int wave = threadIdx.x>>6, lane = threadIdx.x&63;
  if (lane==0){ red[wave]=s; red[4+wave]=ss; }
  __syncthreads();
  s  = red[0]+red[1]+red[2]+red[3];
  ss = red[4]+red[5]+red[6]+red[7];
  float mu  = s * (1.f/D_MODEL);
  float var = ss * (1.f/D_MODEL) - mu*mu;
  float rstd = rsqrtf(var + 1e-6f);
  const float* ar = ada + (size_t)b*(6*D_MODEL);
  float4 gv  = *(const float4*)(g   + d0);
  float4 bv  = *(const float4*)(bta + d0);
  float4 scv = *(const float4*)(ar + sc_off + d0);
  float4 shv = *(const float4*)(ar + sh_off + d0);
  float o0 = ((v.x-mu)*rstd*gv.x + bv.x)*(1.f+scv.x) + shv.x;
  float o1 = ((v.y-mu)*rstd*gv.y + bv.y)*(1.f+scv.y) + shv.y;
  float o2 = ((v.z-mu)*rstd*gv.z + bv.z)*(1.f+scv.z) + shv.z;
  float o3 = ((v.w-mu)*rstd*gv.w + bv.w)*(1.f+scv.w) + shv.w;
  uint2 o;
  o.x = (unsigned)f2b(o0) | ((unsigned)f2b(o1) << 16);
  o.y = (unsigned)f2b(o2) | ((unsigned)f2b(o3) << 16);
  *(uint2*)(out + (size_t)tok*D_MODEL + d0) = o;
}

// ---------------- bf16 MFMA GEMM: C[M,N] = A[M,K] @ BT[N,K]^T ----------------
__global__ __launch_bounds__(256) void gemm_bf16(
    const u16* __restrict__ A, const u16* __restrict__ B,
    float* __restrict__ Cf, u16* __restrict__ Cb,
    int M, int N, int K, const float* __restrict__ aux, int mode,
    long sAz, long sBz, long sCz){
  __shared__ u16 As[128*32];
  __shared__ u16 Bs[128*32];
  int z = blockIdx.z;
  A += (size_t)z * sAz;  B += (size_t)z * sBz;
  size_t cz = (size_t)z * sCz;
  int t = threadIdx.x, w = t >> 6, lane = t & 63;
  int bm = blockIdx.y*128, bn = blockIdx.x*128;
  int srow = lane >> 2, scol = (lane & 3)*8;
  const u16* Ag0 = A + (size_t)(bm + (w*2+0)*16 + srow)*K + scol;
  const u16* Ag1 = A + (size_t)(bm + (w*2+1)*16 + srow)*K + scol;
  const u16* Bg0 = B + (size_t)(bn + (w*2+0)*16 + srow)*K + scol;
  const u16* Bg1 = B + (size_t)(bn + (w*2+1)*16 + srow)*K + scol;
  u16* Al0 = As + (w*2+0)*512;
  u16* Al1 = As + (w*2+1)*512;
  u16* Bl0 = Bs + (w*2+0)*512;
  u16* Bl1 = Bs + (w*2+1)*512;
  int m16 = lane & 15, q8 = (lane >> 4)*8;
  int RO = (w >> 1)*64, CO = (w & 1)*64;
  f32x4 acc[4][4];
  f32x4 zz = {0.f,0.f,0.f,0.f};
  #pragma unroll
  for (int mi=0;mi<4;mi++)
    #pragma unroll
    for (int ni=0;ni<4;ni++) acc[mi][ni] = zz;
  for (int kt = 0; kt < K; kt += 32){
    __syncthreads();
    async16(Ag0, Al0); async16(Ag1, Al1);
    async16(Bg0, Bl0); async16(Bg1, Bl1);
    Ag0 += 32; Ag1 += 32; Bg0 += 32; Bg1 += 32;
    __syncthreads();
    bf16x8 af[4], bfr[4];
    #pragma unroll
    for (int mi=0;mi<4;mi++) af[mi]  = *(const bf16x8*)(As + (RO + mi*16 + m16)*32 + q8);
    #pragma unroll
    for (int ni=0;ni<4;ni++) bfr[ni] = *(const bf16x8*)(Bs + (CO + ni*16 + m16)*32 + q8);
    #pragma unroll
    for (int mi=0;mi<4;mi++)
      #pragma unroll
      for (int ni=0;ni<4;ni++)
        acc[mi][ni] = __builtin_amdgcn_mfma_f32_16x16x32_bf16(af[mi], bfr[ni], acc[mi][ni], 0,0,0);
  }
  int er = (lane >> 4)*4;
  #pragma unroll
  for (int mi=0;mi<4;mi++){
    #pragma unroll
    for (int ni=0;ni<4;ni++){
      #pragma unroll
      for (int r=0;r<4;r++){
        int m = bm + RO + mi*16 + er + r;
        int n = bn + CO + ni*16 + m16;
        size_t idx = cz + (size_t)m*N + n;
        float v = acc[mi][ni][r];
        if (mode == 1) v *= silu_f(aux[idx]);
        if (Cf) Cf[idx] = v;
        if (Cb) Cb[idx] = f2b(v);
      }
    }
  }
}

// ---------------- MFMA flash attention (dense branches) ----------------
// Q,K from QKVb (row stride QKV_LD); V pre-transposed Vt[b*16+h][d][s].
// Each wave owns 16 q rows. mode 0 = grid bias -|q-k|, 1 = none.
__global__ __launch_bounds__(256) void flash_mfma(
    const u16* __restrict__ q, const u16* __restrict__ k, const u16* __restrict__ vt,
    u16* __restrict__ out, int mode){
  __shared__ u16 Ps[64][72];   // 144B rows (16B aligned); per-wave private 16-row slabs
  int t = threadIdx.x, w = t >> 6, lane = t & 63;
  int l4 = lane & 15, quad = lane >> 4;
  int b = blockIdx.z, h = blockIdx.y;
  int qw = blockIdx.x*64 + w*16;                 // wave's first q row
  const u16* qrow = q + (size_t)(b*SEQ + qw + l4)*QKV_LD + h*DH;   // FIX: + h*DH
  bf16x8 qf0 = *(const bf16x8*)(qrow + quad*8);
  bf16x8 qf1 = *(const bf16x8*)(qrow + 32 + quad*8);
  const u16* kbase = k + (size_t)b*SEQ*QKV_LD + h*DH;              // FIX: + h*DH
  const u16* vbase = vt + (size_t)(b*NHEAD + h)*DH*SEQ;
  f32x4 zz = {0.f,0.f,0.f,0.f};
  f32x4 acc_o[4] = {zz,zz,zz,zz};
  float m_run[4] = {-1e30f,-1e30f,-1e30f,-1e30f};
  float l_run[4] = {0.f,0.f,0.f,0.f};
  float qrf[4];
  #pragma unroll
  for (int r=0;r<4;r++) qrf[r] = (float)(qw + quad*4 + r);
  for (int k0 = 0; k0 < SEQ; k0 += 64){
    // ---- QK^T : 4 ntiles x 2 ksteps ----
    f32x4 s[4] = {zz,zz,zz,zz};
    #pragma unroll
    for (int nt=0;nt<4;nt++){
      const u16* kr = kbase + (size_t)(k0 + nt*16 + l4)*QKV_LD;
      bf16x8 kf0 = *(const bf16x8*)(kr + quad*8);
      bf16x8 kf1 = *(const bf16x8*)(kr + 32 + quad*8);
      s[nt] = __builtin_amdgcn_mfma_f32_16x16x32_bf16(qf0, kf0, s[nt], 0,0,0);
      s[nt] = __builtin_amdgcn_mfma_f32_16x16x32_bf16(qf1, kf1, s[nt], 0,0,0);
    }
    // ---- scale + bias ----
    #pragma unroll
    for (int nt=0;nt<4;nt++){
      float kc = (float)(k0 + nt*16 + l4);
      #pragma unroll
      for (int r=0;r<4;r++){
        float v = s[nt][r]*0.125f;
        if (mode==0) v -= fabsf(qrf[r] - kc);
        s[nt][r] = v;
      }
    }
    // ---- online softmax (row stats across cols: nt regs + l4 lanes) ----
    float mt[4];
    #pragma unroll
    for (int r=0;r<4;r++) mt[r] = fmaxf(fmaxf(s[0][r],s[1][r]), fmaxf(s[2][r],s[3][r]));
    #pragma unroll
    for (int off=1; off<16; off<<=1)
      #pragma unroll
      for (int r=0;r<4;r++) mt[r] = fmaxf(mt[r], __shfl_xor(mt[r], off));
    float alpha[4];
    #pragma unroll
    for (int r=0;r<4;r++){
      float mn = fmaxf(m_run[r], mt[r]);
      alpha[r] = __expf(m_run[r] - mn);
      m_run[r] = mn;
    }
    float ps[4] = {0.f,0.f,0.f,0.f};
    #pragma unroll
    for (int nt=0;nt<4;nt++)
      #pragma unroll
      for (int r=0;r<4;r++){
        float p = __expf(s[nt][r] - m_run[r]);
        s[nt][r] = p;
        ps[r] += p;
      }
    #pragma unroll
    for (int off=1; off<16; off<<=1)
      #pragma unroll
      for (int r=0;r<4;r++) ps[r] += __shfl_xor(ps[r], off);
    #pragma unroll
    for (int r=0;r<4;r++) l_run[r] = l_run[r]*alpha[r] + ps[r];
    // ---- store P (bf16) to wave-private LDS slab ----
    #pragma unroll
    for (int nt=0;nt<4;nt++)
      #pragma unroll
      for (int r=0;r<4;r++)
        Ps[w*16 + quad*4 + r][nt*16 + l4] = f2b(s[nt][r]);
    // ---- rescale O ----
    #pragma unroll
    for (int dt=0;dt<4;dt++)
      #pragma unroll
      for (int r=0;r<4;r++) acc_o[dt][r] *= alpha[r];
    __syncthreads();   // fence P write -> A-frag read (cross-lane)
    // ---- PV : P as A-operand, Vt as B-operand ----
    bf16x8 pf0 = *(const bf16x8*)&Ps[w*16 + l4][quad*8];
    bf16x8 pf1 = *(const bf16x8*)&Ps[w*16 + l4][32 + quad*8];
    #pragma unroll
    for (int dt=0;dt<4;dt++){
      const u16* vr = vbase + (size_t)(dt*16 + l4)*SEQ + k0;
      bf16x8 vf0 = *(const bf16x8*)(vr + quad*8);
      bf16x8 vf1 = *(const bf16x8*)(vr + 32 + quad*8);
      acc_o[dt] = __builtin_amdgcn_mfma_f32_16x16x32_bf16(pf0, vf0, acc_o[dt], 0,0,0);
      acc_o[dt] = __builtin_amdgcn_mfma_f32_16x16x32_bf16(pf1, vf1, acc_o[dt], 0,0,0);
    }
  }
  float inv[4];
  #pragma unroll
  for (int r=0;r<4;r++) inv[r] = 1.f/l_run[r];
  #pragma unroll
  for (int dt=0;dt<4;dt++)
    #pragma unroll
    for (int r=0;r<4;r++)
      out[(size_t)(b*SEQ + qw + quad*4 + r)*D_MODEL + h*DH + dt*16 + l4] = f2b(acc_o[dt][r]*inv[r]);
}

// ---------------- sparse attention: reg (k in {q-1,q,q+1}) mode 1, ent (pair) mode 2 ----------------
__global__ __launch_bounds__(256) void sparse_attn_kernel(
    const u16* __restrict__ q, const u16* __restrict__ k, const u16* __restrict__ v,
    u16* __restrict__ out, int mode){
  int wid  = (blockIdx.x * 256 + threadIdx.x) >> 6;
  int lane = threadIdx.x & 63;
  int qpos = wid & (SEQ-1);
  int h    = (wid >> 10) & (NHEAD-1);
  int b    = wid >> 14;
  const size_t rbase = (size_t)b*SEQ*QKV_LD + (size_t)h*DH;
  float qv = b2f(q[rbase + (size_t)qpos*QKV_LD + lane]);
  int ks[3]; int nk = 0;
  if (mode == 1){
    if (qpos > 0) ks[nk++] = qpos-1;
    ks[nk++] = qpos;
    if (qpos < SEQ-1) ks[nk++] = qpos+1;
  } else {
    int k0 = qpos & ~1;
    ks[nk++] = k0; ks[nk++] = k0+1;
  }
  float sc[3], vl[3];
  for (int j=0;j<nk;j++){
    float kv = b2f(k[rbase + (size_t)ks[j]*QKV_LD + lane]);
    float p = qv*kv;
    #pragma unroll
    for (int off=1; off<64; off<<=1) p += __shfl_xor(p, off);
    sc[j] = p * 0.125f;
    vl[j] = b2f(v[rbase + (size_t)ks[j]*QKV_LD + lane]);
  }
  float m = sc[0];
  for (int j=1;j<nk;j++) m = fmaxf(m, sc[j]);
  float l = 0.f, o = 0.f;
  for (int j=0;j<nk;j++){
    float p = __expf(sc[j]-m);
    l += p; o += p*vl[j];
  }
  out[((size_t)b*SEQ + qpos)*D_MODEL + (size_t)h*DH + lane] = f2b(o / l);
}

// ---------------- fusion gate over bf16 branch outputs ----------------
__global__ __launch_bounds__(256) void fusion_kernel(
    const u16* __restrict__ o1, const u16* __restrict__ o2,
    const u16* __restrict__ o3, const u16* __restrict__ o4,
    const float* __restrict__ wg, const float* __restrict__ bg,
    u16* __restrict__ fused){
  __shared__ float red[4][4];
  int tok = blockIdx.x;
  int d0 = threadIdx.x*4;
  size_t base = (size_t)tok*D_MODEL + d0;
  uint2 ra = *(const uint2*)(o1+base);
  uint2 rb = *(const uint2*)(o2+base);
  uint2 rc = *(const uint2*)(o3+base);
  uint2 re = *(const uint2*)(o4+base);
  float av[4] = {b2f(ra.x), b2f(ra.x>>16), b2f(ra.y), b2f(ra.y>>16)};
  float bv[4] = {b2f(rb.x), b2f(rb.x>>16), b2f(rb.y), b2f(rb.y>>16)};
  float cv[4] = {b2f(rc.x), b2f(rc.x>>16), b2f(rc.y), b2f(rc.y>>16)};
  float ev[4] = {b2f(re.x), b2f(re.x>>16), b2f(re.y), b2f(re.y>>16)};
  float lg[4] = {0,0,0,0};
  #pragma unroll
  for (int j=0;j<4;j++){
    int d = d0+j;
    float4 w0 = *(const float4*)(wg + (size_t)(0*D_MODEL+d)*4);
    float4 w1 = *(const float4*)(wg + (size_t)(1*D_MODEL+d)*4);
    float4 w2 = *(const float4*)(wg + (size_t)(2*D_MODEL+d)*4);
    float4 w3 = *(const float4*)(wg + (size_t)(3*D_MODEL+d)*4);
    lg[0] += av[j]*w0.x + bv[j]*w1.x + cv[j]*w2.x + ev[j]*w3.x;
    lg[1] += av[j]*w0.y + bv[j]*w1.y + cv[j]*w2.y + ev[j]*w3.y;
    lg[2] += av[j]*w0.z + bv[j]*w1.z + cv[j]*w2.z + ev[j]*w3.z;
    lg[3] += av[j]*w0.w + bv[j]*w1.w + cv[j]*w2.w + ev[j]*w3.w;
  }
  #pragma unroll
  for (int c=0;c<4;c++)
    #pragma unroll
    for (int off=32; off; off>>=1) lg[c] += __shfl_xor(lg[c], off);
  int wave = threadIdx.x>>6, lane = threadIdx.x&63;
  if (lane==0){ red[wave][0]=lg[0]; red[wave][1]=lg[1]; red[wave][2]=lg[2]; red[wave][3]=lg[3]; }
  __syncthreads();
  float logit[4];
  #pragma unroll
  for (int c=0;c<4;c++) logit[c] = red[0][c]+red[1][c]+red[2][c]+red[3][c] + bg[c];
  float m = fmaxf(fmaxf(logit[0],logit[1]), fmaxf(logit[2],logit[3]));
  float e0=__expf(logit[0]-m), e1=__expf(logit[1]-m), e2=__expf(logit[2]-m), e3=__expf(logit[3]-m);
  float inv = 1.f/(e0+e1+e2+e3);
  float g0=e0*inv, g1=e1*inv, g2=e2*inv, g3=e3*inv;
  float f0 = g0*av[0] + g1*bv[0] + g2*cv[0] + g3*ev[0];
  float f1 = g0*av[1] + g1*bv[1] + g2*cv[1] + g3*ev[1];
  float f2 = g0*av[2] + g1*bv[2] + g2*cv[2] + g3*ev[2];
  float f3 = g0*av[3] + g1*bv[3] + g2*cv[3] + g3*ev[3];
  uint2 o;
  o.x = (unsigned)f2b(f0) | ((unsigned)f2b(f1) << 16);
  o.y = (unsigned)f2b(f2) | ((unsigned)f2b(f3) << 16);
  *(uint2*)(fused+base) = o;
}

// ---------------- residual: out = xin + ada[b, g_off + d] * t ----------------
__global__ __launch_bounds__(256) void resid_kernel(
    const float* __restrict__ xin, const float* __restrict__ ada, int g_off,
    const float* __restrict__ t, float* __restrict__ out){
  size_t i = ((size_t)blockIdx.x*256 + threadIdx.x)*4;
  int b = (int)(i >> 20);
  int d = (int)(i & (D_MODEL-1));
  float4 xv = *(const float4*)(xin + i);
  float4 tv = *(const float4*)(t + i);
  float4 gv = *(const float4*)(ada + (size_t)b*(6*D_MODEL) + g_off + d);
  float4 o;
  o.x = xv.x + gv.x*tv.x;
  o.y = xv.y + gv.y*tv.y;
  o.z = xv.z + gv.z*tv.z;
  o.w = xv.w + gv.w*tv.w;
  *(float4*)(out + i) = o;
}

extern "C" void kernel_launch(void* const* d_in, const int* in_sizes, int n_in,
                              void* d_out, int out_size, void* d_ws, size_t ws_size,
                              hipStream_t stream){
  (void)in_sizes; (void)n_in; (void)out_size; (void)ws_size;
  const float* x      = (const float*)d_in[0];
  const float* t_emb  = (const float*)d_in[1];
  const float* ln1_g  = (const float*)d_in[2];
  const float* ln1_b  = (const float*)d_in[3];
  const float* ln2_g  = (const float*)d_in[4];
  const float* ln2_b  = (const float*)d_in[5];
  const float* ada_w  = (const float*)d_in[6];
  const float* ada_b  = (const float*)d_in[7];
  const float* fus_wg = (const float*)d_in[8];
  const float* fus_bg = (const float*)d_in[9];
  const float* fus_wo = (const float*)d_in[10];
  const float* ffn_w1 = (const float*)d_in[11];
  const float* ffn_w2 = (const float*)d_in[12];
  const float* ffn_w3 = (const float*)d_in[13];
  const float* aw[4][4];
  for (int p=0;p<4;p++)
    for (int w=0;w<4;w++)
      aw[p][w] = (const float*)d_in[14 + p*4 + w];

  const size_t MB = 1u<<20;
  char* ws = (char*)d_ws;
  u16*   WSQ  = (u16*)(ws);              // 17 x [1024,1024] bf16 = 34MB
  u16*   W13  = (u16*)(ws + 34*MB);      // w1T, w3T [4096,1024] x2 = 16MB
  u16*   W2T  = (u16*)(ws + 50*MB);      // w2T [1024,4096] = 8MB
  u16*   NX   = (u16*)(ws + 58*MB);      // nx / nx2 bf16 = 8MB
  u16*   QKVb = (u16*)(ws + 66*MB);      // [4096,12288] bf16 = 96MB
  float* G1   = (float*)(ws + 66*MB);    //   overlay after attn: 64MB
  u16*   H    = (u16*)(ws + 130*MB);     //   overlay: 32MB
  u16*   AO   = (u16*)(ws + 166*MB);     // [4][4096,1024] bf16 = 32MB
  u16*   FUSED= (u16*)(ws + 166*MB);     //   overlay after wo-GEMM: 8MB
  float* T1   = (float*)(ws + 174*MB);   //   overlay: 16MB (also FFN_OUT)
  u16*   OB   = (u16*)(ws + 198*MB);     // [4][4096,1024] bf16 = 32MB (dead during attention)
  u16*   VT   = (u16*)(ws + 198*MB);     //   overlay during attention: [2][64][64][1024] bf16 = 16MB
  float* X1   = (float*)(ws + 230*MB);   // 16MB
  float* ADAB = (float*)(ws + 246*MB);   // [4,6144] fp32

  u16* WOW  = WSQ + (size_t)12*1024*1024;
  u16* FUSW = WSQ + (size_t)16*1024*1024;
  u16* W3T  = W13 + (size_t)4096*1024;

  dim3 b256(256);
  // 0) weight convert+transpose
  Ptrs psq{};
  for (int p=0;p<4;p++) for (int w2=0;w2<3;w2++) psq.p[p*3+w2] = aw[p][w2];
  for (int p=0;p<4;p++) psq.p[12+p] = aw[p][3];
  psq.p[16] = fus_wo;
  transpose_cvt<<<dim3(32,32,17), b256, 0, stream>>>(psq, WSQ, 1024, 1024);
  Ptrs p13{}; p13.p[0]=ffn_w1; p13.p[1]=ffn_w3;
  transpose_cvt<<<dim3(128,32,2), b256, 0, stream>>>(p13, W13, 1024, 4096);
  Ptrs p2{}; p2.p[0]=ffn_w2;
  transpose_cvt<<<dim3(32,128,1), b256, 0, stream>>>(p2, W2T, 4096, 1024);

  // 1) ada + ln1
  ada_kernel<<<dim3(6*D_MODEL/256, BATCH), b256, 0, stream>>>(t_emb, ada_w, ada_b, ADAB);
  ln_mod_kernel<<<NTOK, b256, 0, stream>>>(x, ln1_g, ln1_b, ADAB, 0, D_MODEL, NX);

  // 2) all QKV projections in one GEMM
  gemm_bf16<<<dim3(QKV_LD/128, NTOK/128, 1), b256, 0, stream>>>(
      NX, WSQ, nullptr, QKVb, NTOK, QKV_LD, 1024, nullptr, 0, 0,0,0);

  // 2b) pre-transpose V for dense branches
  transpose_v<<<dim3(SEQ/64, BATCH*NHEAD, 2), b256, 0, stream>>>(QKVb, VT);

  // 3) attention branches -> AO[p]
  for (int p=0;p<4;p++){
    const u16* qp = QKVb + p*3072;
    const u16* kp = qp + 1024;
    const u16* vp = qp + 2048;
    u16* aop = AO + (size_t)p*NTOK*D_MODEL;
    if (p==0)
      flash_mfma<<<dim3(SEQ/64, NHEAD, BATCH), b256, 0, stream>>>(
          qp, kp, VT, aop, 0);
    else if (p==3)
      flash_mfma<<<dim3(SEQ/64, NHEAD, BATCH), b256, 0, stream>>>(
          qp, kp, VT + (size_t)64*DH*SEQ, aop, 1);
    else
      sparse_attn_kernel<<<dim3(BATCH*NHEAD*SEQ/4), b256, 0, stream>>>(qp, kp, vp, aop, p);
  }

  // 4) batched output projections
  gemm_bf16<<<dim3(1024/128, NTOK/128, 4), b256, 0, stream>>>(
      AO, WOW, nullptr, OB, NTOK, 1024, 1024, nullptr, 0,
      (long)NTOK*1024, (long)1024*1024, (long)NTOK*1024);

  // 5) fusion gate
  fusion_kernel<<<NTOK, b256, 0, stream>>>(
      OB, OB + (size_t)NTOK*D_MODEL, OB + (size_t)2*NTOK*D_MODEL, OB + (size_t)3*NTOK*D_MODEL,
      fus_wg, fus_bg, FUSED);

  // 6) t1 = fused @ fus_wo (fp32)
  gemm_bf16<<<dim3(1024/128, NTOK/128, 1), b256, 0, stream>>>(
      FUSED, FUSW, T1, nullptr, NTOK, 1024, 1024, nullptr, 0, 0,0,0);

  // 7) x1 = x + g_m * t1
  resid_kernel<<<dim3(NTOK*D_MODEL/1024), b256, 0, stream>>>(x, ADAB, 2*D_MODEL, T1, X1);

  // 8) nx2 = modulated LN2(x1)
  ln_mod_kernel<<<NTOK, b256, 0, stream>>>(X1, ln2_g, ln2_b, ADAB, 3*D_MODEL, 4*D_MODEL, NX);

  // 9) G1 = nx2 @ w1 (fp32)
  gemm_bf16<<<dim3(FFDIM/128, NTOK/128, 1), b256, 0, stream>>>(
      NX, W13, G1, nullptr, NTOK, FFDIM, 1024, nullptr, 0, 0,0,0);

  // 10) H = silu(G1) * (nx2 @ w3)  (bf16)
  gemm_bf16<<<dim3(FFDIM/128, NTOK/128, 1), b256, 0, stream>>>(
      NX, W3T, nullptr, H, NTOK, FFDIM, 1024, G1, 1, 0,0,0);

  // 11) ffn_out = H @ w2 (fp32, reuse T1)
  gemm_bf16<<<dim3(1024/128, NTOK/128, 1), b256, 0, stream>>>(
      H, W2T, T1, nullptr, NTOK, 1024, FFDIM, nullptr, 0, 0,0,0);

  // 12) out = x1 + g_f * ffn_out
  resid_kernel<<<dim3(NTOK*D_MODEL/1024), b256, 0, stream>>>(X1, ADAB, 5*D_MODEL, T1, (float*)d_out);
}

// Round 5
// 1198.429 us; speedup vs baseline: 4.2191x; 1.0215x over previous
//
#include <hip/hip_runtime.h>
#include <cstddef>
#include <cstdint>

// (B,S,D,H,F) = (4,1024,1024,16,4096)
#define D_MODEL 1024
#define SEQ     1024
#define BATCH   4
#define NHEAD   16
#define DH      64
#define FFDIM   4096
#define NTOK    4096
#define QKV_LD  12288   // 4 branches x (q,k,v) x 1024

typedef unsigned short u16;
typedef __bf16 bf16x8 __attribute__((ext_vector_type(8)));
typedef float  f32x4  __attribute__((ext_vector_type(4)));

__device__ __forceinline__ u16 f2b(float f){
  unsigned u = __builtin_bit_cast(unsigned, f);
  u += 0x7FFFu + ((u >> 16) & 1u);          // RNE
  return (u16)(u >> 16);
}
__device__ __forceinline__ float b2f(unsigned h){
  unsigned u = (h & 0xffffu) << 16;
  return __builtin_bit_cast(float, u);
}
__device__ __forceinline__ float silu_f(float x){ return x / (1.f + __expf(-x)); }

__device__ __forceinline__ void async16(const u16* g, u16* l){
  __builtin_amdgcn_global_load_lds((__attribute__((address_space(1))) void*)(g),
                                   (__attribute__((address_space(3))) void*)(l), 16, 0, 0);
}

// ---------------- weight transpose+convert: src fp32 [K,N] -> dst bf16 [N,K] ----------------
struct Ptrs { const float* p[17]; };
__global__ __launch_bounds__(256) void transpose_cvt(Ptrs ps, u16* __restrict__ dst, int K, int N){
  __shared__ float tile[32][33];
  const float* __restrict__ src = ps.p[blockIdx.z];
  u16* d = dst + (size_t)blockIdx.z * K * N;
  int n0 = blockIdx.x*32, k0 = blockIdx.y*32;
  int tx = threadIdx.x & 31, ty = threadIdx.x >> 5;
  #pragma unroll
  for (int i=0;i<4;i++){ int kk = ty + i*8; tile[kk][tx] = src[(size_t)(k0+kk)*N + n0+tx]; }
  __syncthreads();
  #pragma unroll
  for (int i=0;i<4;i++){ int nn = ty + i*8; d[(size_t)(n0+nn)*K + k0+tx] = f2b(tile[tx][nn]); }
}

// ---------------- V pre-transpose for dense branches: Vt[branch2][b*16+h][d][s] bf16 ----------------
__global__ __launch_bounds__(256) void transpose_v(const u16* __restrict__ qkv, u16* __restrict__ vt){
  __shared__ u16 tile[64][72];
  int s0 = blockIdx.x*64;
  int bh = blockIdx.y;          // b*16+h
  int p2 = blockIdx.z;          // 0 -> branch 0 (grid), 1 -> branch 3 (sem)
  int p  = p2 ? 3 : 0;
  int b = bh >> 4, h = bh & 15;
  const u16* src = qkv + (size_t)b*SEQ*QKV_LD + p*3072 + 2048 + h*64;
  int t = threadIdx.x;
  int r = t >> 3, c8 = (t & 7)*8;
  #pragma unroll
  for (int i=0;i<2;i++){
    int s = r + i*32;
    *(uint4*)&tile[s][c8] = *(const uint4*)(src + (size_t)(s0+s)*QKV_LD + c8);
  }
  __syncthreads();
  u16* dst = vt + ((size_t)p2*64 + bh)*DH*SEQ;
  #pragma unroll
  for (int i=0;i<2;i++){
    int d = r + i*32;
    u16 tmp[8];
    #pragma unroll
    for (int j=0;j<8;j++) tmp[j] = tile[c8+j][d];
    *(uint4*)(dst + (size_t)d*SEQ + s0 + c8) = *(uint4*)tmp;
  }
}

// ---------------- ada = silu(t_emb) @ ada_w + ada_b  -> [B, 6D] fp32 ----------------
__global__ __launch_bounds__(256) void ada_kernel(
    const float* __restrict__ t_emb, const float* __restrict__ W,
    const float* __restrict__ bias, float* __restrict__ out){
  __shared__ float st[D_MODEL];
  int b = blockIdx.y;
  for (int i = threadIdx.x; i < D_MODEL; i += 256) st[i] = silu_f(t_emb[b*D_MODEL + i]);
  __syncthreads();
  int n = blockIdx.x*256 + threadIdx.x;
  float acc = bias[n];
  for (int k = 0; k < D_MODEL; ++k) acc += st[k] * W[(size_t)k*(6*D_MODEL) + n];
  out[(size_t)b*(6*D_MODEL) + n] = acc;
}

// ---------------- nx = (ln(x)*g+b)*(1+sc)+sh -> bf16 ----------------
__global__ __launch_bounds__(256) void ln_mod_kernel(
    const float* __restrict__ x, const float* __restrict__ g, const float* __restrict__ bta,
    const float* __restrict__ ada, int sh_off, int sc_off, u16* __restrict__ out){
  __shared__ float red[8];
  int tok = blockIdx.x;
  int b = tok >> 10;
  const float* xr = x + (size_t)tok*D_MODEL;
  int d0 = threadIdx.x*4;
  float4 v = *(const float4*)(xr + d0);
  float s  = v.x+v.y+v.z+v.w;
  float ss = v.x*v.x+v.y*v.y+v.z*v.z+v.w*v.w;
  #pragma unroll
  for (int off=32; off; off>>=1){ s += __shfl_xor(s,off); ss += __shfl_xor(ss,off); }
  int wave = threadIdx.x>>6, lane = threadIdx.x&63;
  if (lane==0){ red[wave]=s; red[4+wave]=ss; }
  __syncthreads();
  s  = red[0]+red[1]+red[2]+red[3];
  ss = red[4]+red[5]+red[6]+red[7];
  float mu  = s * (1.f/D_MODEL);
  float var = ss * (1.f/D_MODEL) - mu*mu;
  float rstd = rsqrtf(var + 1e-6f);
  const float* ar = ada + (size_t)b*(6*D_MODEL);
  float4 gv  = *(const float4*)(g   + d0);
  float4 bv  = *(const float4*)(bta + d0);
  float4 scv = *(const float4*)(ar + sc_off + d0);
  float4 shv = *(const float4*)(ar + sh_off + d0);
  float o0 = ((v.x-mu)*rstd*gv.x + bv.x)*(1.f+scv.x) + shv.x;
  float o1 = ((v.y-mu)*rstd*gv.y + bv.y)*(1.f+scv.y) + shv.y;
  float o2 = ((v.z-mu)*rstd*gv.z + bv.z)*(1.f+scv.z) + shv.z;
  float o3 = ((v.w-mu)*rstd*gv.w + bv.w)*(1.f+scv.w) + shv.w;
  uint2 o;
  o.x = (unsigned)f2b(o0) | ((unsigned)f2b(o1) << 16);
  o.y = (unsigned)f2b(o2) | ((unsigned)f2b(o3) << 16);
  *(uint2*)(out + (size_t)tok*D_MODEL + d0) = o;
}

// ---------------- bf16 MFMA GEMM: C[M,N] = A[M,K] @ BT[N,K]^T ----------------
// 128x128 tile, BK=32. Operand-swapped MFMA (B as A-operand) so each lane's
// 4 acc values are 4 CONSECUTIVE columns -> packed 8B (bf16) / 16B (fp32) stores.
__global__ __launch_bounds__(256) void gemm_bf16(
    const u16* __restrict__ A, const u16* __restrict__ B,
    float* __restrict__ Cf, u16* __restrict__ Cb,
    int M, int N, int K,
    long sAz, long sBz, long sCz){
  __shared__ u16 As[128*32];
  __shared__ u16 Bs[128*32];
  int z = blockIdx.z;
  A += (size_t)z * sAz;  B += (size_t)z * sBz;
  size_t cz = (size_t)z * sCz;
  int t = threadIdx.x, w = t >> 6, lane = t & 63;
  int bm = blockIdx.y*128, bn = blockIdx.x*128;
  int srow = lane >> 2, scol = (lane & 3)*8;
  const u16* Ag0 = A + (size_t)(bm + (w*2+0)*16 + srow)*K + scol;
  const u16* Ag1 = A + (size_t)(bm + (w*2+1)*16 + srow)*K + scol;
  const u16* Bg0 = B + (size_t)(bn + (w*2+0)*16 + srow)*K + scol;
  const u16* Bg1 = B + (size_t)(bn + (w*2+1)*16 + srow)*K + scol;
  u16* Al0 = As + (w*2+0)*512;
  u16* Al1 = As + (w*2+1)*512;
  u16* Bl0 = Bs + (w*2+0)*512;
  u16* Bl1 = Bs + (w*2+1)*512;
  int m16 = lane & 15, q8 = (lane >> 4)*8;
  int RO = (w >> 1)*64, CO = (w & 1)*64;
  f32x4 acc[4][4];
  f32x4 zz = {0.f,0.f,0.f,0.f};
  #pragma unroll
  for (int mi=0;mi<4;mi++)
    #pragma unroll
    for (int ni=0;ni<4;ni++) acc[mi][ni] = zz;
  for (int kt = 0; kt < K; kt += 32){
    __syncthreads();
    async16(Ag0, Al0); async16(Ag1, Al1);
    async16(Bg0, Bl0); async16(Bg1, Bl1);
    Ag0 += 32; Ag1 += 32; Bg0 += 32; Bg1 += 32;
    __syncthreads();
    bf16x8 af[4], bfr[4];
    #pragma unroll
    for (int mi=0;mi<4;mi++) af[mi]  = *(const bf16x8*)(As + (RO + mi*16 + m16)*32 + q8);
    #pragma unroll
    for (int ni=0;ni<4;ni++) bfr[ni] = *(const bf16x8*)(Bs + (CO + ni*16 + m16)*32 + q8);
    #pragma unroll
    for (int mi=0;mi<4;mi++)
      #pragma unroll
      for (int ni=0;ni<4;ni++)
        acc[mi][ni] = __builtin_amdgcn_mfma_f32_16x16x32_bf16(bfr[ni], af[mi], acc[mi][ni], 0,0,0);
  }
  // D layout with swapped operands: col(lane&15) = m-index, row(quad*4+r) = n-index
  int quad = lane >> 4;
  #pragma unroll
  for (int mi=0;mi<4;mi++){
    int m = bm + RO + mi*16 + m16;
    #pragma unroll
    for (int ni=0;ni<4;ni++){
      int n0 = bn + CO + ni*16 + quad*4;
      size_t idx = cz + (size_t)m*N + n0;
      f32x4 v = acc[mi][ni];
      if (Cf) *(float4*)(Cf + idx) = make_float4(v[0], v[1], v[2], v[3]);
      if (Cb){
        uint2 pk;
        pk.x = (unsigned)f2b(v[0]) | ((unsigned)f2b(v[1]) << 16);
        pk.y = (unsigned)f2b(v[2]) | ((unsigned)f2b(v[3]) << 16);
        *(uint2*)(Cb + idx) = pk;
      }
    }
  }
}

// ---------------- swiglu: H[m][f] = silu(FF[m][f]) * FF[m][f+4096], bf16 ----------------
__global__ __launch_bounds__(256) void swiglu_kernel(const u16* __restrict__ FF, u16* __restrict__ H){
  size_t i = ((size_t)blockIdx.x*256 + threadIdx.x)*8;   // index into [4096*4096]
  int m = (int)(i >> 12);
  int f = (int)(i & 4095);
  const u16* row = FF + (size_t)m*(2*FFDIM);
  uint4 a = *(const uint4*)(row + f);
  uint4 b = *(const uint4*)(row + FFDIM + f);
  unsigned au[4] = {a.x,a.y,a.z,a.w};
  unsigned bu[4] = {b.x,b.y,b.z,b.w};
  unsigned ou[4];
  #pragma unroll
  for (int j=0;j<4;j++){
    float g0 = b2f(au[j]), g1 = b2f(au[j]>>16);
    float x0 = b2f(bu[j]), x1 = b2f(bu[j]>>16);
    ou[j] = (unsigned)f2b(silu_f(g0)*x0) | ((unsigned)f2b(silu_f(g1)*x1) << 16);
  }
  uint4 o = {ou[0],ou[1],ou[2],ou[3]};
  *(uint4*)(H + i) = o;
}

// ---------------- MFMA flash attention (dense branches) ----------------
__global__ __launch_bounds__(256) void flash_mfma(
    const u16* __restrict__ q, const u16* __restrict__ k, const u16* __restrict__ vt,
    u16* __restrict__ out, int mode){
  __shared__ u16 Ps[64][72];
  int t = threadIdx.x, w = t >> 6, lane = t & 63;
  int l4 = lane & 15, quad = lane >> 4;
  int b = blockIdx.z, h = blockIdx.y;
  int qw = blockIdx.x*64 + w*16;
  const u16* qrow = q + (size_t)(b*SEQ + qw + l4)*QKV_LD + h*DH;
  bf16x8 qf0 = *(const bf16x8*)(qrow + quad*8);
  bf16x8 qf1 = *(const bf16x8*)(qrow + 32 + quad*8);
  const u16* kbase = k + (size_t)b*SEQ*QKV_LD + h*DH;
  const u16* vbase = vt + (size_t)(b*NHEAD + h)*DH*SEQ;
  f32x4 zz = {0.f,0.f,0.f,0.f};
  f32x4 acc_o[4] = {zz,zz,zz,zz};
  float m_run[4] = {-1e30f,-1e30f,-1e30f,-1e30f};
  float l_run[4] = {0.f,0.f,0.f,0.f};
  float qrf[4];
  #pragma unroll
  for (int r=0;r<4;r++) qrf[r] = (float)(qw + quad*4 + r);
  for (int k0 = 0; k0 < SEQ; k0 += 64){
    f32x4 s[4] = {zz,zz,zz,zz};
    #pragma unroll
    for (int nt=0;nt<4;nt++){
      const u16* kr = kbase + (size_t)(k0 + nt*16 + l4)*QKV_LD;
      bf16x8 kf0 = *(const bf16x8*)(kr + quad*8);
      bf16x8 kf1 = *(const bf16x8*)(kr + 32 + quad*8);
      s[nt] = __builtin_amdgcn_mfma_f32_16x16x32_bf16(qf0, kf0, s[nt], 0,0,0);
      s[nt] = __builtin_amdgcn_mfma_f32_16x16x32_bf16(qf1, kf1, s[nt], 0,0,0);
    }
    #pragma unroll
    for (int nt=0;nt<4;nt++){
      float kc = (float)(k0 + nt*16 + l4);
      #pragma unroll
      for (int r=0;r<4;r++){
        float v = s[nt][r]*0.125f;
        if (mode==0) v -= fabsf(qrf[r] - kc);
        s[nt][r] = v;
      }
    }
    float mt[4];
    #pragma unroll
    for (int r=0;r<4;r++) mt[r] = fmaxf(fmaxf(s[0][r],s[1][r]), fmaxf(s[2][r],s[3][r]));
    #pragma unroll
    for (int off=1; off<16; off<<=1)
      #pragma unroll
      for (int r=0;r<4;r++) mt[r] = fmaxf(mt[r], __shfl_xor(mt[r], off));
    float alpha[4];
    #pragma unroll
    for (int r=0;r<4;r++){
      float mn = fmaxf(m_run[r], mt[r]);
      alpha[r] = __expf(m_run[r] - mn);
      m_run[r] = mn;
    }
    float ps[4] = {0.f,0.f,0.f,0.f};
    #pragma unroll
    for (int nt=0;nt<4;nt++)
      #pragma unroll
      for (int r=0;r<4;r++){
        float p = __expf(s[nt][r] - m_run[r]);
        s[nt][r] = p;
        ps[r] += p;
      }
    #pragma unroll
    for (int off=1; off<16; off<<=1)
      #pragma unroll
      for (int r=0;r<4;r++) ps[r] += __shfl_xor(ps[r], off);
    #pragma unroll
    for (int r=0;r<4;r++) l_run[r] = l_run[r]*alpha[r] + ps[r];
    #pragma unroll
    for (int nt=0;nt<4;nt++)
      #pragma unroll
      for (int r=0;r<4;r++)
        Ps[w*16 + quad*4 + r][nt*16 + l4] = f2b(s[nt][r]);
    #pragma unroll
    for (int dt=0;dt<4;dt++)
      #pragma unroll
      for (int r=0;r<4;r++) acc_o[dt][r] *= alpha[r];
    __syncthreads();
    bf16x8 pf0 = *(const bf16x8*)&Ps[w*16 + l4][quad*8];
    bf16x8 pf1 = *(const bf16x8*)&Ps[w*16 + l4][32 + quad*8];
    #pragma unroll
    for (int dt=0;dt<4;dt++){
      const u16* vr = vbase + (size_t)(dt*16 + l4)*SEQ + k0;
      bf16x8 vf0 = *(const bf16x8*)(vr + quad*8);
      bf16x8 vf1 = *(const bf16x8*)(vr + 32 + quad*8);
      acc_o[dt] = __builtin_amdgcn_mfma_f32_16x16x32_bf16(pf0, vf0, acc_o[dt], 0,0,0);
      acc_o[dt] = __builtin_amdgcn_mfma_f32_16x16x32_bf16(pf1, vf1, acc_o[dt], 0,0,0);
    }
  }
  float inv[4];
  #pragma unroll
  for (int r=0;r<4;r++) inv[r] = 1.f/l_run[r];
  #pragma unroll
  for (int dt=0;dt<4;dt++)
    #pragma unroll
    for (int r=0;r<4;r++)
      out[(size_t)(b*SEQ + qw + quad*4 + r)*D_MODEL + h*DH + dt*16 + l4] = f2b(acc_o[dt][r]*inv[r]);
}

// ---------------- sparse attention: reg (k in {q-1,q,q+1}) mode 1, ent (pair) mode 2 ----------------
__global__ __launch_bounds__(256) void sparse_attn_kernel(
    const u16* __restrict__ q, const u16* __restrict__ k, const u16* __restrict__ v,
    u16* __restrict__ out, int mode){
  int wid  = (blockIdx.x * 256 + threadIdx.x) >> 6;
  int lane = threadIdx.x & 63;
  int qpos = wid & (SEQ-1);
  int h    = (wid >> 10) & (NHEAD-1);
  int b    = wid >> 14;
  const size_t rbase = (size_t)b*SEQ*QKV_LD + (size_t)h*DH;
  float qv = b2f(q[rbase + (size_t)qpos*QKV_LD + lane]);
  int ks[3]; int nk = 0;
  if (mode == 1){
    if (qpos > 0) ks[nk++] = qpos-1;
    ks[nk++] = qpos;
    if (qpos < SEQ-1) ks[nk++] = qpos+1;
  } else {
    int k0 = qpos & ~1;
    ks[nk++] = k0; ks[nk++] = k0+1;
  }
  float sc[3], vl[3];
  for (int j=0;j<nk;j++){
    float kv = b2f(k[rbase + (size_t)ks[j]*QKV_LD + lane]);
    float p = qv*kv;
    #pragma unroll
    for (int off=1; off<64; off<<=1) p += __shfl_xor(p, off);
    sc[j] = p * 0.125f;
    vl[j] = b2f(v[rbase + (size_t)ks[j]*QKV_LD + lane]);
  }
  float m = sc[0];
  for (int j=1;j<nk;j++) m = fmaxf(m, sc[j]);
  float l = 0.f, o = 0.f;
  for (int j=0;j<nk;j++){
    float p = __expf(sc[j]-m);
    l += p; o += p*vl[j];
  }
  out[((size_t)b*SEQ + qpos)*D_MODEL + (size_t)h*DH + lane] = f2b(o / l);
}

// ---------------- fusion gate over bf16 branch outputs ----------------
__global__ __launch_bounds__(256) void fusion_kernel(
    const u16* __restrict__ o1, const u16* __restrict__ o2,
    const u16* __restrict__ o3, const u16* __restrict__ o4,
    const float* __restrict__ wg, const float* __restrict__ bg,
    u16* __restrict__ fused){
  __shared__ float red[4][4];
  int tok = blockIdx.x;
  int d0 = threadIdx.x*4;
  size_t base = (size_t)tok*D_MODEL + d0;
  uint2 ra = *(const uint2*)(o1+base);
  uint2 rb = *(const uint2*)(o2+base);
  uint2 rc = *(const uint2*)(o3+base);
  uint2 re = *(const uint2*)(o4+base);
  float av[4] = {b2f(ra.x), b2f(ra.x>>16), b2f(ra.y), b2f(ra.y>>16)};
  float bv[4] = {b2f(rb.x), b2f(rb.x>>16), b2f(rb.y), b2f(rb.y>>16)};
  float cv[4] = {b2f(rc.x), b2f(rc.x>>16), b2f(rc.y), b2f(rc.y>>16)};
  float ev[4] = {b2f(re.x), b2f(re.x>>16), b2f(re.y), b2f(re.y>>16)};
  float lg[4] = {0,0,0,0};
  #pragma unroll
  for (int j=0;j<4;j++){
    int d = d0+j;
    float4 w0 = *(const float4*)(wg + (size_t)(0*D_MODEL+d)*4);
    float4 w1 = *(const float4*)(wg + (size_t)(1*D_MODEL+d)*4);
    float4 w2 = *(const float4*)(wg + (size_t)(2*D_MODEL+d)*4);
    float4 w3 = *(const float4*)(wg + (size_t)(3*D_MODEL+d)*4);
    lg[0] += av[j]*w0.x + bv[j]*w1.x + cv[j]*w2.x + ev[j]*w3.x;
    lg[1] += av[j]*w0.y + bv[j]*w1.y + cv[j]*w2.y + ev[j]*w3.y;
    lg[2] += av[j]*w0.z + bv[j]*w1.z + cv[j]*w2.z + ev[j]*w3.z;
    lg[3] += av[j]*w0.w + bv[j]*w1.w + cv[j]*w2.w + ev[j]*w3.w;
  }
  #pragma unroll
  for (int c=0;c<4;c++)
    #pragma unroll
    for (int off=32; off; off>>=1) lg[c] += __shfl_xor(lg[c], off);
  int wave = threadIdx.x>>6, lane = threadIdx.x&63;
  if (lane==0){ red[wave][0]=lg[0]; red[wave][1]=lg[1]; red[wave][2]=lg[2]; red[wave][3]=lg[3]; }
  __syncthreads();
  float logit[4];
  #pragma unroll
  for (int c=0;c<4;c++) logit[c] = red[0][c]+red[1][c]+red[2][c]+red[3][c] + bg[c];
  float m = fmaxf(fmaxf(logit[0],logit[1]), fmaxf(logit[2],logit[3]));
  float e0=__expf(logit[0]-m), e1=__expf(logit[1]-m), e2=__expf(logit[2]-m), e3=__expf(logit[3]-m);
  float inv = 1.f/(e0+e1+e2+e3);
  float g0=e0*inv, g1=e1*inv, g2=e2*inv, g3=e3*inv;
  float f0 = g0*av[0] + g1*bv[0] + g2*cv[0] + g3*ev[0];
  float f1 = g0*av[1] + g1*bv[1] + g2*cv[1] + g3*ev[1];
  float f2 = g0*av[2] + g1*bv[2] + g2*cv[2] + g3*ev[2];
  float f3 = g0*av[3] + g1*bv[3] + g2*cv[3] + g3*ev[3];
  uint2 o;
  o.x = (unsigned)f2b(f0) | ((unsigned)f2b(f1) << 16);
  o.y = (unsigned)f2b(f2) | ((unsigned)f2b(f3) << 16);
  *(uint2*)(fused+base) = o;
}

// ---------------- residual: out = xin + ada[b, g_off + d] * t ----------------
__global__ __launch_bounds__(256) void resid_kernel(
    const float* __restrict__ xin, const float* __restrict__ ada, int g_off,
    const float* __restrict__ t, float* __restrict__ out){
  size_t i = ((size_t)blockIdx.x*256 + threadIdx.x)*4;
  int b = (int)(i >> 20);
  int d = (int)(i & (D_MODEL-1));
  float4 xv = *(const float4*)(xin + i);
  float4 tv = *(const float4*)(t + i);
  float4 gv = *(const float4*)(ada + (size_t)b*(6*D_MODEL) + g_off + d);
  float4 o;
  o.x = xv.x + gv.x*tv.x;
  o.y = xv.y + gv.y*tv.y;
  o.z = xv.z + gv.z*tv.z;
  o.w = xv.w + gv.w*tv.w;
  *(float4*)(out + i) = o;
}

extern "C" void kernel_launch(void* const* d_in, const int* in_sizes, int n_in,
                              void* d_out, int out_size, void* d_ws, size_t ws_size,
                              hipStream_t stream){
  (void)in_sizes; (void)n_in; (void)out_size; (void)ws_size;
  const float* x      = (const float*)d_in[0];
  const float* t_emb  = (const float*)d_in[1];
  const float* ln1_g  = (const float*)d_in[2];
  const float* ln1_b  = (const float*)d_in[3];
  const float* ln2_g  = (const float*)d_in[4];
  const float* ln2_b  = (const float*)d_in[5];
  const float* ada_w  = (const float*)d_in[6];
  const float* ada_b  = (const float*)d_in[7];
  const float* fus_wg = (const float*)d_in[8];
  const float* fus_bg = (const float*)d_in[9];
  const float* fus_wo = (const float*)d_in[10];
  const float* ffn_w1 = (const float*)d_in[11];
  const float* ffn_w2 = (const float*)d_in[12];
  const float* ffn_w3 = (const float*)d_in[13];
  const float* aw[4][4];
  for (int p=0;p<4;p++)
    for (int w=0;w<4;w++)
      aw[p][w] = (const float*)d_in[14 + p*4 + w];

  const size_t MB = 1u<<20;
  char* ws = (char*)d_ws;
  u16*   WSQ  = (u16*)(ws);              // 17 x [1024,1024] bf16 = 34MB
  u16*   W13  = (u16*)(ws + 34*MB);      // [8192,1024] bf16 = 16MB (w1T then w3T)
  u16*   W2T  = (u16*)(ws + 50*MB);      // w2T [1024,4096] = 8MB
  u16*   NX   = (u16*)(ws + 58*MB);      // nx / nx2 bf16 = 8MB
  u16*   QKVb = (u16*)(ws + 66*MB);      // [4096,12288] bf16 = 96MB
  u16*   FF   = (u16*)(ws + 66*MB);      //   overlay after attn+outproj: [4096,8192] bf16 = 64MB
  u16*   H    = (u16*)(ws + 130*MB);     //   [4096,4096] bf16 = 32MB
  u16*   AO   = (u16*)(ws + 166*MB);     // [4][4096,1024] bf16 = 32MB
  u16*   FUSED= (u16*)(ws + 166*MB);     //   overlay after wo-GEMM: 8MB
  float* T1   = (float*)(ws + 174*MB);   //   16MB (also FFN_OUT)
  u16*   OB   = (u16*)(ws + 198*MB);     // [4][4096,1024] bf16 = 32MB (dead during attention)
  u16*   VT   = (u16*)(ws + 198*MB);     //   overlay during attention: 16MB
  float* X1   = (float*)(ws + 230*MB);   // 16MB
  float* ADAB = (float*)(ws + 246*MB);   // [4,6144] fp32

  u16* WOW  = WSQ + (size_t)12*1024*1024;
  u16* FUSW = WSQ + (size_t)16*1024*1024;

  dim3 b256(256);
  // 0) weight convert+transpose
  Ptrs psq{};
  for (int p=0;p<4;p++) for (int w2=0;w2<3;w2++) psq.p[p*3+w2] = aw[p][w2];
  for (int p=0;p<4;p++) psq.p[12+p] = aw[p][3];
  psq.p[16] = fus_wo;
  transpose_cvt<<<dim3(32,32,17), b256, 0, stream>>>(psq, WSQ, 1024, 1024);
  Ptrs p13{}; p13.p[0]=ffn_w1; p13.p[1]=ffn_w3;
  transpose_cvt<<<dim3(128,32,2), b256, 0, stream>>>(p13, W13, 1024, 4096);
  Ptrs p2{}; p2.p[0]=ffn_w2;
  transpose_cvt<<<dim3(32,128,1), b256, 0, stream>>>(p2, W2T, 4096, 1024);

  // 1) ada + ln1
  ada_kernel<<<dim3(6*D_MODEL/256, BATCH), b256, 0, stream>>>(t_emb, ada_w, ada_b, ADAB);
  ln_mod_kernel<<<NTOK, b256, 0, stream>>>(x, ln1_g, ln1_b, ADAB, 0, D_MODEL, NX);

  // 2) all QKV projections in one GEMM
  gemm_bf16<<<dim3(QKV_LD/128, NTOK/128, 1), b256, 0, stream>>>(
      NX, WSQ, nullptr, QKVb, NTOK, QKV_LD, 1024, 0,0,0);

  // 2b) pre-transpose V for dense branches
  transpose_v<<<dim3(SEQ/64, BATCH*NHEAD, 2), b256, 0, stream>>>(QKVb, VT);

  // 3) attention branches -> AO[p]
  for (int p=0;p<4;p++){
    const u16* qp = QKVb + p*3072;
    const u16* kp = qp + 1024;
    const u16* vp = qp + 2048;
    u16* aop = AO + (size_t)p*NTOK*D_MODEL;
    if (p==0)
      flash_mfma<<<dim3(SEQ/64, NHEAD, BATCH), b256, 0, stream>>>(qp, kp, VT, aop, 0);
    else if (p==3)
      flash_mfma<<<dim3(SEQ/64, NHEAD, BATCH), b256, 0, stream>>>(
          qp, kp, VT + (size_t)64*DH*SEQ, aop, 1);
    else
      sparse_attn_kernel<<<dim3(BATCH*NHEAD*SEQ/4), b256, 0, stream>>>(qp, kp, vp, aop, p);
  }

  // 4) batched output projections
  gemm_bf16<<<dim3(1024/128, NTOK/128, 4), b256, 0, stream>>>(
      AO, WOW, nullptr, OB, NTOK, 1024, 1024,
      (long)NTOK*1024, (long)1024*1024, (long)NTOK*1024);

  // 5) fusion gate
  fusion_kernel<<<NTOK, b256, 0, stream>>>(
      OB, OB + (size_t)NTOK*D_MODEL, OB + (size_t)2*NTOK*D_MODEL, OB + (size_t)3*NTOK*D_MODEL,
      fus_wg, fus_bg, FUSED);

  // 6) t1 = fused @ fus_wo (fp32)
  gemm_bf16<<<dim3(1024/128, NTOK/128, 1), b256, 0, stream>>>(
      FUSED, FUSW, T1, nullptr, NTOK, 1024, 1024, 0,0,0);

  // 7) x1 = x + g_m * t1
  resid_kernel<<<dim3(NTOK*D_MODEL/1024), b256, 0, stream>>>(x, ADAB, 2*D_MODEL, T1, X1);

  // 8) nx2 = modulated LN2(x1)
  ln_mod_kernel<<<NTOK, b256, 0, stream>>>(X1, ln2_g, ln2_b, ADAB, 3*D_MODEL, 4*D_MODEL, NX);

  // 9) FF = nx2 @ [w1 | w3]  (bf16, N=8192; QKVb is dead now)
  gemm_bf16<<<dim3((2*FFDIM)/128, NTOK/128, 1), b256, 0, stream>>>(
      NX, W13, nullptr, FF, NTOK, 2*FFDIM, 1024, 0,0,0);

  // 10) H = silu(FF[:, :4096]) * FF[:, 4096:]
  swiglu_kernel<<<dim3((size_t)NTOK*FFDIM/8/256), b256, 0, stream>>>(FF, H);

  // 11) ffn_out = H @ w2 (fp32, reuse T1)
  gemm_bf16<<<dim3(1024/128, NTOK/128, 1), b256, 0, stream>>>(
      H, W2T, T1, nullptr, NTOK, 1024, FFDIM, 0,0,0);

  // 12) out = x1 + g_f * ffn_out
  resid_kernel<<<dim3(NTOK*D_MODEL/1024), b256, 0, stream>>>(X1, ADAB, 5*D_MODEL, T1, (float*)d_out);
}